// Round 4
// baseline (759.248 us; speedup 1.0000x reference)
//
#include <hip/hip_runtime.h>
#include <stdint.h>

typedef __attribute__((ext_vector_type(8))) short s16x8;
typedef __attribute__((ext_vector_type(4))) float f32x4;

#define GLD_LDS16(gp, lp) __builtin_amdgcn_global_load_lds( \
    (__attribute__((address_space(1))) void*)(void*)(gp), \
    (__attribute__((address_space(3))) void*)(lp), 16, 0, 0)

__device__ __forceinline__ float b2f(unsigned short s) {
    unsigned int u = ((unsigned int)s) << 16;
    return __builtin_bit_cast(float, u);
}
__device__ __forceinline__ unsigned short f2b(float f) {
    unsigned int u = __builtin_bit_cast(unsigned int, f);
    u = (u + 0x7FFFu + ((u >> 16) & 1u)) >> 16;
    return (unsigned short)u;
}
__device__ __forceinline__ f32x4 mfma16(s16x8 a, s16x8 b, f32x4 c) {
    return __builtin_amdgcn_mfma_f32_16x16x32_bf16(a, b, c, 0, 0, 0);
}
template <int N> __device__ __forceinline__ void waitvm() {
    if constexpr (N == 0) asm volatile("s_waitcnt vmcnt(0)" ::: "memory");
    else if constexpr (N == 1) asm volatile("s_waitcnt vmcnt(1)" ::: "memory");
    else if constexpr (N == 2) asm volatile("s_waitcnt vmcnt(2)" ::: "memory");
    else if constexpr (N == 4) asm volatile("s_waitcnt vmcnt(4)" ::: "memory");
}

// ---------------- RMSNorm (fp32 in -> bf16 out), D = 2048 ----------------
__global__ __launch_bounds__(256) void rmsnorm_bf16(
    const float* __restrict__ x, const float* __restrict__ wgt,
    unsigned short* __restrict__ out)
{
    const int row = blockIdx.x;
    const int t = threadIdx.x;
    const float* xr = x + (size_t)row * 2048;
    float4 a = *(const float4*)(xr + t * 8);
    float4 b = *(const float4*)(xr + t * 8 + 4);
    float ss = a.x*a.x + a.y*a.y + a.z*a.z + a.w*a.w
             + b.x*b.x + b.y*b.y + b.z*b.z + b.w*b.w;
    #pragma unroll
    for (int d = 1; d < 64; d <<= 1) ss += __shfl_xor(ss, d);
    __shared__ float red[4];
    if ((t & 63) == 0) red[t >> 6] = ss;
    __syncthreads();
    float tot = red[0] + red[1] + red[2] + red[3];
    float inv = rsqrtf(tot * (1.0f / 2048.0f) + 1e-5f);
    float vals[8] = {a.x, a.y, a.z, a.w, b.x, b.y, b.z, b.w};
    const float* wr_ = wgt + t * 8;
    s16x8 ov;
    #pragma unroll
    for (int j = 0; j < 8; ++j) ov[j] = (short)f2b(vals[j] * inv * wr_[j]);
    *(s16x8*)(out + (size_t)row * 2048 + t * 8) = ov;
}

// ------------- transpose + convert: in fp32 [K][N] -> out bf16 [N][K] -------------
__global__ __launch_bounds__(256) void transpose_to_bf16(
    const float* __restrict__ in, unsigned short* __restrict__ out, int K, int N)
{
    __shared__ float tile[32][33];
    int n0 = blockIdx.x * 32, k0 = blockIdx.y * 32;
    int r = threadIdx.x >> 5, c = threadIdx.x & 31;
    #pragma unroll
    for (int i = 0; i < 4; ++i)
        tile[r + i * 8][c] = in[(size_t)(k0 + r + i * 8) * N + n0 + c];
    __syncthreads();
    #pragma unroll
    for (int i = 0; i < 4; ++i)
        out[(size_t)(n0 + r + i * 8) * K + k0 + c] = f2b(tile[c][r + i * 8]);
}

// ---------------- Quadrant-phase GEMM (m201-style schedule) ----------------
// C[4096,N] = A[4096,K] * B[N,K]^T, bf16 in, fp32 acc. Tile BM x BN, BK=64,
// 8 waves (2M x 4N), per-wave (BM/2)x(BN/4). LDS [rows][64] with permuted row
// order (stage-units = phase-need order) and chunk-XOR swizzle (zero-conflict).
// Per K-tile: 4 phases = C-quadrants; each {ds_read frags; stage one unit-group
// of tile t+1; barrier; lgkm0; MFMA quadrant}; vmcnt waits ONLY at ph0-end
// (ALOADS/2) and ph3-end (BLOADS/2) — loads span ~4 phases before being waited.
// EPI 0: C bf16.  EPI 1: C fp32 = acc+ADD.  EPI 2: C bf16 = silu(acc)*C_prev.
template <int BM, int BN, int EPI>
__global__ __launch_bounds__(512, 2) void gemmq(
    const unsigned short* __restrict__ A,
    const unsigned short* __restrict__ B,
    void* __restrict__ Cv,
    const float* __restrict__ ADD,
    int N, int K)
{
    constexpr int MIQ = BM / 64;       // A frags per quadrant
    constexpr int NJQ = BN / 128;      // B frags per quadrant
    constexpr int ABUF = BM * 64;
    constexpr int BBUF = BN * 64;
    constexpr int ALOADS = BM / 64;    // 8KB stage units per K-tile
    constexpr int BLOADS = BN / 64;
    constexpr int MT = 4096 / BM;
    __shared__ __align__(16) unsigned short As[2 * ABUF];
    __shared__ __align__(16) unsigned short Bs[2 * BBUF];

    const int t = threadIdx.x;
    const int l = t & 63;
    const int w = t >> 6;
    const int l15 = l & 15, lg = l >> 4;
    const int wr = w >> 2, wc = w & 3;

    // fragment-read chunk offsets (chunk-XOR swizzle; row&7 == l15&7)
    const int cA0 = ((lg) ^ (l15 & 7)) * 8;
    const int cA1 = ((4 + lg) ^ (l15 & 7)) * 8;

    // bijective XCD-aware block swizzle (m204)
    const int nwg = (int)gridDim.x;
    const int orig = (int)blockIdx.x;
    const int q8 = nwg >> 3, r8 = nwg & 7;
    const int xcd = orig & 7, lid = orig >> 3;
    const int wg = (xcd < r8 ? xcd * (q8 + 1) : r8 * (q8 + 1) + (xcd - r8) * q8) + lid;
    const int m0 = (wg % MT) * BM;
    const int n0 = (wg / MT) * BN;

    // stage pointers: thread t writes LDS row (unit*64 + t>>3), chunk t&7;
    // source row = row-permutation (stage-units ordered by phase need), source
    // col chunk pre-swizzled so read-side XOR matches (both-sides rule).
    const int tr = t >> 3;
    const int scol = ((t & 7) ^ (tr & 7)) * 8;
    const unsigned short* pA[ALOADS];
    #pragma unroll
    for (int s = 0; s < ALOADS; ++s) {
        int rho = s * 64 + tr;
        int g = (rho % (BM / 4)) + ((rho / (BM / 4)) & 1) * (BM / 2) + (rho / (BM / 2)) * (BM / 4);
        pA[s] = A + (size_t)(m0 + g) * K + scol;
    }
    const unsigned short* pB[BLOADS];
    #pragma unroll
    for (int s = 0; s < BLOADS; ++s) {
        int rho = s * 64 + tr;
        int g = (rho % (BN / 8)) + ((rho / (BN / 8)) & 3) * (BN / 4) + (rho / (BN / 2)) * (BN / 8);
        pB[s] = B + (size_t)(n0 + g) * K + scol;
    }

    f32x4 acc[2][2][MIQ][NJQ] = {};
    s16x8 aF[MIQ][2];
    s16x8 bF[2][NJQ][2];

    const int NT = K / 64;

    // prologue: stage tile 0 into buf0 (A then B), full drain
    #pragma unroll
    for (int s = 0; s < ALOADS; ++s) GLD_LDS16(pA[s], &As[s * 4096 + t * 8]);
    #pragma unroll
    for (int s = 0; s < BLOADS; ++s) GLD_LDS16(pB[s], &Bs[s * 4096 + t * 8]);
    waitvm<0>();
    __builtin_amdgcn_s_barrier();

    for (int kt = 0; kt < NT; ++kt) {
        const int rb  = (kt & 1) ? ABUF : 0;
        const int rbB = (kt & 1) ? BBUF : 0;
        const int wb  = ABUF - rb;
        const int wbB = BBUF - rbB;
        const int knext = (kt + 1 < NT ? kt + 1 : kt) * 64;

        // ================= phase 0: quadrant (0,0) =================
        #pragma unroll
        for (int i = 0; i < MIQ; ++i) {
            const int rho = wr * (BM / 4) + i * 16 + l15;
            aF[i][0] = *(const s16x8*)&As[rb + rho * 64 + cA0];
            aF[i][1] = *(const s16x8*)&As[rb + rho * 64 + cA1];
        }
        #pragma unroll
        for (int j = 0; j < NJQ; ++j) {
            const int rho = wc * (BN / 8) + j * 16 + l15;
            bF[0][j][0] = *(const s16x8*)&Bs[rbB + rho * 64 + cA0];
            bF[0][j][1] = *(const s16x8*)&Bs[rbB + rho * 64 + cA1];
        }
        #pragma unroll
        for (int s = 0; s < ALOADS / 2; ++s)
            GLD_LDS16(pA[s] + knext, &As[wb + s * 4096 + t * 8]);
        if constexpr (MIQ * 2 + NJQ * 2 >= 12)
            asm volatile("s_waitcnt lgkmcnt(8)" ::: "memory");
        __builtin_amdgcn_s_barrier();
        asm volatile("s_waitcnt lgkmcnt(0)" ::: "memory");
        __builtin_amdgcn_sched_barrier(0);
        __builtin_amdgcn_s_setprio(1);
        #pragma unroll
        for (int kk = 0; kk < 2; ++kk)
            #pragma unroll
            for (int i = 0; i < MIQ; ++i)
                #pragma unroll
                for (int j = 0; j < NJQ; ++j)
                    acc[0][0][i][j] = mfma16(aF[i][kk], bF[0][j][kk], acc[0][0][i][j]);
        __builtin_amdgcn_s_setprio(0);
        __builtin_amdgcn_sched_barrier(0);
        waitvm<ALOADS / 2>();            // retires B1 of THIS tile's stage set
        __builtin_amdgcn_s_barrier();

        // ================= phase 1: quadrant (0,1) =================
        #pragma unroll
        for (int j = 0; j < NJQ; ++j) {
            const int rho = (BN / 2) + wc * (BN / 8) + j * 16 + l15;
            bF[1][j][0] = *(const s16x8*)&Bs[rbB + rho * 64 + cA0];
            bF[1][j][1] = *(const s16x8*)&Bs[rbB + rho * 64 + cA1];
        }
        #pragma unroll
        for (int s = ALOADS / 2; s < ALOADS; ++s)
            GLD_LDS16(pA[s] + knext, &As[wb + s * 4096 + t * 8]);
        __builtin_amdgcn_s_barrier();
        asm volatile("s_waitcnt lgkmcnt(0)" ::: "memory");
        __builtin_amdgcn_sched_barrier(0);
        __builtin_amdgcn_s_setprio(1);
        #pragma unroll
        for (int kk = 0; kk < 2; ++kk)
            #pragma unroll
            for (int i = 0; i < MIQ; ++i)
                #pragma unroll
                for (int j = 0; j < NJQ; ++j)
                    acc[0][1][i][j] = mfma16(aF[i][kk], bF[1][j][kk], acc[0][1][i][j]);
        __builtin_amdgcn_s_setprio(0);
        __builtin_amdgcn_sched_barrier(0);
        __builtin_amdgcn_s_barrier();

        // ================= phase 2: quadrant (1,0) =================
        #pragma unroll
        for (int i = 0; i < MIQ; ++i) {
            const int rho = (BM / 2) + wr * (BM / 4) + i * 16 + l15;
            aF[i][0] = *(const s16x8*)&As[rb + rho * 64 + cA0];
            aF[i][1] = *(const s16x8*)&As[rb + rho * 64 + cA1];
        }
        #pragma unroll
        for (int s = 0; s < BLOADS / 2; ++s)
            GLD_LDS16(pB[s] + knext, &Bs[wbB + s * 4096 + t * 8]);
        __builtin_amdgcn_s_barrier();
        asm volatile("s_waitcnt lgkmcnt(0)" ::: "memory");
        __builtin_amdgcn_sched_barrier(0);
        __builtin_amdgcn_s_setprio(1);
        #pragma unroll
        for (int kk = 0; kk < 2; ++kk)
            #pragma unroll
            for (int i = 0; i < MIQ; ++i)
                #pragma unroll
                for (int j = 0; j < NJQ; ++j)
                    acc[1][0][i][j] = mfma16(aF[i][kk], bF[0][j][kk], acc[1][0][i][j]);
        __builtin_amdgcn_s_setprio(0);
        __builtin_amdgcn_sched_barrier(0);
        __builtin_amdgcn_s_barrier();

        // ================= phase 3: quadrant (1,1) =================
        #pragma unroll
        for (int s = BLOADS / 2; s < BLOADS; ++s)
            GLD_LDS16(pB[s] + knext, &Bs[wbB + s * 4096 + t * 8]);
        __builtin_amdgcn_s_barrier();
        __builtin_amdgcn_s_setprio(1);
        #pragma unroll
        for (int kk = 0; kk < 2; ++kk)
            #pragma unroll
            for (int i = 0; i < MIQ; ++i)
                #pragma unroll
                for (int j = 0; j < NJQ; ++j)
                    acc[1][1][i][j] = mfma16(aF[i][kk], bF[1][j][kk], acc[1][1][i][j]);
        __builtin_amdgcn_s_setprio(0);
        __builtin_amdgcn_sched_barrier(0);
        waitvm<BLOADS / 2>();            // retires ...,Alo,Ahi,B0 of next tile
        __builtin_amdgcn_s_barrier();
    }

    // ---------------- epilogue ----------------
    #pragma unroll
    for (int qm = 0; qm < 2; ++qm)
        #pragma unroll
        for (int i = 0; i < MIQ; ++i)
            #pragma unroll
            for (int r = 0; r < 4; ++r) {
                const int row = m0 + wr * (BM / 2) + qm * (BM / 4) + i * 16 + lg * 4 + r;
                const size_t rbase = (size_t)row * N;
                #pragma unroll
                for (int qn = 0; qn < 2; ++qn)
                    #pragma unroll
                    for (int j = 0; j < NJQ; ++j) {
                        const int col = n0 + wc * (BN / 4) + qn * (BN / 8) + j * 16 + l15;
                        float v = acc[qm][qn][i][j][r];
                        if constexpr (EPI == 0) {
                            ((unsigned short*)Cv)[rbase + col] = f2b(v);
                        } else if constexpr (EPI == 1) {
                            ((float*)Cv)[rbase + col] = v + ADD[rbase + col];
                        } else {
                            unsigned short* Cb = (unsigned short*)Cv;
                            float y = b2f(Cb[rbase + col]);
                            float sg = v / (1.0f + expf(-v));
                            Cb[rbase + col] = f2b(sg * y);
                        }
                    }
            }
}

// ---------------- RoPE table: [S][32] of (cos, sin) ----------------
__global__ void rope_tab_k(float2* __restrict__ tab) {
    int i = blockIdx.x * 256 + threadIdx.x;
    if (i >= 4096 * 32) return;
    int s = i >> 5, d = i & 31;
    float inv = exp2f(-(float)d * (13.287712379549449f / 32.0f));
    float fr = (float)s * inv;
    float sv, cv;
    sincosf(fr, &sv, &cv);
    tab[i] = make_float2(cv, sv);
}

// ---------------- RoPE apply (in-place on qkv, q heads + k heads) ----------------
__global__ void rope_apply_k(unsigned short* __restrict__ qkv, const float2* __restrict__ tab) {
    int i = blockIdx.x * 256 + threadIdx.x;
    if (i >= 4096 * 40 * 4) return;
    int dg = i & 3;
    int rest = i >> 2;
    int head = rest % 40;
    int s = rest / 40;
    int off = head < 32 ? head * 64 : 2048 + (head - 32) * 64;
    unsigned short* p = qkv + (size_t)s * 3072 + off + dg * 8;
    s16x8 x1 = *(const s16x8*)p;
    s16x8 x2 = *(const s16x8*)(p + 32);
    const float2* tb = tab + s * 32 + dg * 8;
    s16x8 o1, o2;
    #pragma unroll
    for (int j = 0; j < 8; ++j) {
        float2 cs = tb[j];
        float a = b2f((unsigned short)x1[j]);
        float b = b2f((unsigned short)x2[j]);
        o1[j] = (short)f2b(a * cs.x - b * cs.y);
        o2[j] = (short)f2b(b * cs.x + a * cs.y);
    }
    *(s16x8*)p = o1;
    *(s16x8*)(p + 32) = o2;
}

// ---------------- Sliding-window attention, flash-style ----------------
__global__ __launch_bounds__(256) void attn_swa(
    const unsigned short* __restrict__ qkv,
    unsigned short* __restrict__ out)
{
    constexpr int LDQ = 3072;
    const int qb = blockIdx.x;
    const int h = blockIdx.y;
    const int kvh = h >> 2;
    const int q0 = qb * 64;
    const int t = threadIdx.x, l = t & 63, w = t >> 6;
    const int l15 = l & 15, lg = l >> 4;

    __shared__ unsigned short Kl[64 * 64];
    __shared__ unsigned short Vt[64 * 72];
    __shared__ unsigned short Pl[4 * 16 * 72];

    s16x8 qf[2];
    {
        const unsigned short* qp = qkv + (size_t)(q0 + w * 16 + l15) * LDQ + h * 64 + lg * 8;
        qf[0] = *(const s16x8*)(qp);
        qf[1] = *(const s16x8*)(qp + 32);
    }
    float m_run[4] = {-1e30f, -1e30f, -1e30f, -1e30f};
    float l_run[4] = {0.f, 0.f, 0.f, 0.f};
    f32x4 o[4] = {};

    const float SC = 0.0625f * 1.4426950408889634f;
    const int kt_lo = qb >= 8 ? qb - 8 : 0;

    for (int kt = kt_lo; kt <= qb; ++kt) {
        const int ks = kt * 64;
        __syncthreads();
        {
            const unsigned short* kg = qkv + (size_t)(ks + (t >> 3)) * LDQ + 2048 + kvh * 64 + (t & 7) * 8;
            GLD_LDS16(kg, Kl + t * 8);
            GLD_LDS16(kg + (size_t)32 * LDQ, Kl + t * 8 + 2048);
        }
        {
            const unsigned short* vg = qkv + (size_t)(ks + l) * LDQ + 2560 + kvh * 64 + w * 16;
            s16x8 v0 = *(const s16x8*)vg;
            s16x8 v1 = *(const s16x8*)(vg + 8);
            #pragma unroll
            for (int j = 0; j < 8; ++j) Vt[(w * 16 + j) * 72 + l] = (unsigned short)v0[j];
            #pragma unroll
            for (int j = 0; j < 8; ++j) Vt[(w * 16 + 8 + j) * 72 + l] = (unsigned short)v1[j];
        }
        __syncthreads();

        f32x4 sf[4] = {};
        #pragma unroll
        for (int kf = 0; kf < 4; ++kf) {
            #pragma unroll
            for (int kk = 0; kk < 2; ++kk) {
                s16x8 kb = *(const s16x8*)(Kl + (kf * 16 + l15) * 64 + kk * 32 + lg * 8);
                sf[kf] = mfma16(qf[kk], kb, sf[kf]);
            }
        }

        float tmax[4];
        #pragma unroll
        for (int r = 0; r < 4; ++r) {
            int qrow = q0 + w * 16 + lg * 4 + r;
            float mx = -1e30f;
            #pragma unroll
            for (int kf = 0; kf < 4; ++kf) {
                int key = ks + kf * 16 + l15;
                bool valid = (key <= qrow) && (qrow - key < 512);
                if (valid) mx = fmaxf(mx, sf[kf][r]);
            }
            #pragma unroll
            for (int d2 = 1; d2 < 16; d2 <<= 1) mx = fmaxf(mx, __shfl_xor(mx, d2));
            tmax[r] = mx;
        }

        float alpha[4], rsum[4];
        #pragma unroll
        for (int r = 0; r < 4; ++r) {
            float mnew = fmaxf(m_run[r], tmax[r]);
            alpha[r] = exp2f((m_run[r] - mnew) * SC);
            m_run[r] = mnew;
            rsum[r] = 0.f;
        }

        unsigned short* Pw = Pl + w * (16 * 72);
        #pragma unroll
        for (int kf = 0; kf < 4; ++kf) {
            #pragma unroll
            for (int r = 0; r < 4; ++r) {
                int qrow = q0 + w * 16 + lg * 4 + r;
                int key = ks + kf * 16 + l15;
                bool valid = (key <= qrow) && (qrow - key < 512);
                float p = valid ? exp2f((sf[kf][r] - m_run[r]) * SC) : 0.f;
                rsum[r] += p;
                Pw[(lg * 4 + r) * 72 + kf * 16 + l15] = f2b(p);
            }
        }
        #pragma unroll
        for (int r = 0; r < 4; ++r) {
            #pragma unroll
            for (int d2 = 1; d2 < 16; d2 <<= 1) rsum[r] += __shfl_xor(rsum[r], d2);
            l_run[r] = l_run[r] * alpha[r] + rsum[r];
        }
        #pragma unroll
        for (int hf = 0; hf < 4; ++hf)
            #pragma unroll
            for (int r = 0; r < 4; ++r) o[hf][r] *= alpha[r];

        asm volatile("s_waitcnt lgkmcnt(0)" ::: "memory");
        __builtin_amdgcn_sched_barrier(0);

        #pragma unroll
        for (int kk2 = 0; kk2 < 2; ++kk2) {
            s16x8 pa = *(const s16x8*)(Pw + l15 * 72 + kk2 * 32 + lg * 8);
            #pragma unroll
            for (int hf = 0; hf < 4; ++hf) {
                s16x8 vb = *(const s16x8*)(Vt + (hf * 16 + l15) * 72 + kk2 * 32 + lg * 8);
                o[hf] = mfma16(pa, vb, o[hf]);
            }
        }
    }

    #pragma unroll
    for (int r = 0; r < 4; ++r) {
        int qrow = q0 + w * 16 + lg * 4 + r;
        float invl = 1.0f / l_run[r];
        unsigned short* orow = out + (size_t)qrow * 2048 + h * 64;
        #pragma unroll
        for (int hf = 0; hf < 4; ++hf)
            orow[hf * 16 + l15] = f2b(o[hf][r] * invl);
    }
}

extern "C" void kernel_launch(void* const* d_in, const int* in_sizes, int n_in,
                              void* d_out, int out_size, void* d_ws, size_t ws_size,
                              hipStream_t stream)
{
    const float* hidden = (const float*)d_in[0];
    const float* w_mix  = (const float*)d_in[1];
    const float* wq     = (const float*)d_in[2];
    const float* wk     = (const float*)d_in[3];
    const float* wv     = (const float*)d_in[4];
    const float* wo     = (const float*)d_in[5];
    const float* w_mlp  = (const float*)d_in[6];
    const float* wg     = (const float*)d_in[7];
    const float* wd     = (const float*)d_in[8];
    float* out = (float*)d_out;

    char* ws = (char*)d_ws;
    size_t off = 0;
    auto alloc = [&](size_t bytes) {
        char* p = ws + off;
        off += (bytes + 255) & ~(size_t)255;
        return p;
    };
    unsigned short* Wt   = (unsigned short*)alloc((size_t)11264 * 2048 * 2);
    unsigned short* xn   = (unsigned short*)alloc((size_t)4096 * 2048 * 2);
    unsigned short* qkv  = (unsigned short*)alloc((size_t)4096 * 3072 * 2);
    float2*         rtab = (float2*)alloc((size_t)4096 * 32 * 8);
    unsigned short* attn = (unsigned short*)alloc((size_t)4096 * 2048 * 2);
    float*          hbuf = (float*)alloc((size_t)4096 * 2048 * 4);
    unsigned short* act  = (unsigned short*)alloc((size_t)4096 * 5632 * 2);

    // 1. x = rmsnorm(hidden) -> bf16
    rmsnorm_bf16<<<4096, 256, 0, stream>>>(hidden, w_mix, xn);

    // 2. W^T for q,k,v concatenated
    transpose_to_bf16<<<dim3(64, 64), 256, 0, stream>>>(wq, Wt, 2048, 2048);
    transpose_to_bf16<<<dim3(16, 64), 256, 0, stream>>>(wk, Wt + (size_t)2048 * 2048, 2048, 512);
    transpose_to_bf16<<<dim3(16, 64), 256, 0, stream>>>(wv, Wt + (size_t)2560 * 2048, 2048, 512);

    // 3. qkv = x @ [wq|wk|wv]   (N=3072, K=2048) tile 256x256 -> 192 blocks
    gemmq<256, 256, 0><<<192, 512, 0, stream>>>(xn, Wt, qkv, nullptr, 3072, 2048);

    // 4. RoPE
    rope_tab_k<<<(4096 * 32 + 255) / 256, 256, 0, stream>>>(rtab);
    rope_apply_k<<<(4096 * 40 * 4 + 255) / 256, 256, 0, stream>>>(qkv, rtab);

    // 5. sliding-window attention
    attn_swa<<<dim3(64, 32), 256, 0, stream>>>(qkv, attn);

    // 6. h = hidden + attn @ wo   (N=2048) tile 128x256 -> 256 blocks
    transpose_to_bf16<<<dim3(64, 64), 256, 0, stream>>>(wo, Wt, 2048, 2048);
    gemmq<128, 256, 1><<<256, 512, 0, stream>>>(attn, Wt, hbuf, hidden, 2048, 2048);

    // 7. xn2 = rmsnorm(h)
    rmsnorm_bf16<<<4096, 256, 0, stream>>>(hbuf, w_mlp, xn);

    // 8. MLP: act = y; act = silu(gate) * act   (N=5632) tile 128x256 -> 704 blocks
    transpose_to_bf16<<<dim3(352, 64), 256, 0, stream>>>(wg, Wt, 2048, 11264);
    gemmq<128, 256, 0><<<704, 512, 0, stream>>>(xn, Wt + (size_t)5632 * 2048, act, nullptr, 5632, 2048);
    gemmq<128, 256, 2><<<704, 512, 0, stream>>>(xn, Wt, act, nullptr, 5632, 2048);

    // 9. out = h + act @ w_down   (N=2048, K=5632) tile 128x256 -> 256 blocks
    transpose_to_bf16<<<dim3(64, 176), 256, 0, stream>>>(wd, Wt, 5632, 2048);
    gemmq<128, 256, 1><<<256, 512, 0, stream>>>(act, Wt, out, hbuf, 2048, 5632);
}

// Round 5
// 637.931 us; speedup vs baseline: 1.1902x; 1.1902x over previous
//
#include <hip/hip_runtime.h>
#include <stdint.h>

typedef __attribute__((ext_vector_type(8))) short s16x8;
typedef __attribute__((ext_vector_type(4))) float f32x4;

#define GLD_LDS16(gp, lp) __builtin_amdgcn_global_load_lds( \
    (__attribute__((address_space(1))) void*)(void*)(gp), \
    (__attribute__((address_space(3))) void*)(lp), 16, 0, 0)

__device__ __forceinline__ float b2f(unsigned short s) {
    unsigned int u = ((unsigned int)s) << 16;
    return __builtin_bit_cast(float, u);
}
__device__ __forceinline__ unsigned short f2b(float f) {
    unsigned int u = __builtin_bit_cast(unsigned int, f);
    u = (u + 0x7FFFu + ((u >> 16) & 1u)) >> 16;
    return (unsigned short)u;
}
__device__ __forceinline__ f32x4 mfma16(s16x8 a, s16x8 b, f32x4 c) {
    return __builtin_amdgcn_mfma_f32_16x16x32_bf16(a, b, c, 0, 0, 0);
}
template <int N> __device__ __forceinline__ void waitvm() {
    if constexpr (N == 2) asm volatile("s_waitcnt vmcnt(2)" ::: "memory");
    else if constexpr (N == 3) asm volatile("s_waitcnt vmcnt(3)" ::: "memory");
    else if constexpr (N == 4) asm volatile("s_waitcnt vmcnt(4)" ::: "memory");
}

// ---------------- RMSNorm (fp32 in -> bf16 out), D = 2048 ----------------
__global__ __launch_bounds__(256) void rmsnorm_bf16(
    const float* __restrict__ x, const float* __restrict__ wgt,
    unsigned short* __restrict__ out)
{
    const int row = blockIdx.x;
    const int t = threadIdx.x;
    const float* xr = x + (size_t)row * 2048;
    float4 a = *(const float4*)(xr + t * 8);
    float4 b = *(const float4*)(xr + t * 8 + 4);
    float ss = a.x*a.x + a.y*a.y + a.z*a.z + a.w*a.w
             + b.x*b.x + b.y*b.y + b.z*b.z + b.w*b.w;
    #pragma unroll
    for (int d = 1; d < 64; d <<= 1) ss += __shfl_xor(ss, d);
    __shared__ float red[4];
    if ((t & 63) == 0) red[t >> 6] = ss;
    __syncthreads();
    float tot = red[0] + red[1] + red[2] + red[3];
    float inv = rsqrtf(tot * (1.0f / 2048.0f) + 1e-5f);
    float vals[8] = {a.x, a.y, a.z, a.w, b.x, b.y, b.z, b.w};
    const float* wr_ = wgt + t * 8;
    s16x8 ov;
    #pragma unroll
    for (int j = 0; j < 8; ++j) ov[j] = (short)f2b(vals[j] * inv * wr_[j]);
    *(s16x8*)(out + (size_t)row * 2048 + t * 8) = ov;
}

// ------------- transpose + convert: in fp32 [K][N] -> out bf16 [N][K] -------------
__global__ __launch_bounds__(256) void transpose_to_bf16(
    const float* __restrict__ in, unsigned short* __restrict__ out, int K, int N)
{
    __shared__ float tile[32][33];
    int n0 = blockIdx.x * 32, k0 = blockIdx.y * 32;
    int r = threadIdx.x >> 5, c = threadIdx.x & 31;
    #pragma unroll
    for (int i = 0; i < 4; ++i)
        tile[r + i * 8][c] = in[(size_t)(k0 + r + i * 8) * N + n0 + c];
    __syncthreads();
    #pragma unroll
    for (int i = 0; i < 4; ++i)
        out[(size_t)(n0 + r + i * 8) * K + k0 + c] = f2b(tile[c][r + i * 8]);
}

// ---------------- m201-geometry GEMM: C[4096,N] = A[4096,K] * B[N,K]^T ----------------
// BM=256, BN in {256,128}. 8 waves (2M x 4N), per-wave 128 x (BN/4). BK=64.
// 4 quadrant-phases per K-tile, 16 (BN=256) / 8 (BN=128) MFMA per phase.
// A-half frags reused across 2 phases; B-half across 2 phases; ph3 reads nothing.
// One half-tile staged per phase (order A0,B0,A1,B1 of tile t+1), LDS double-
// buffered by K-tile parity. Counted vmcnt at TWO points per K-tile only:
// end-ph0 vmcnt(2) [retires A1,B1 of current tile], end-ph3 vmcnt(2+LBH)
// [retires A0,B0 of next tile] -> every load has >=2-phase issue-to-wait distance.
// Chunk-XOR LDS swizzle (both-sides): physical chunk = logical ^ (lrow&7).
// EPI 0: C bf16.  EPI 1: C fp32 = acc+ADD.  EPI 2: C bf16 = silu(acc)*C_prev.
template <int BN, int EPI>
__global__ __launch_bounds__(512, 2) void gemmq(
    const unsigned short* __restrict__ A,
    const unsigned short* __restrict__ B,
    void* __restrict__ Cv,
    const float* __restrict__ ADD,
    int N, int K)
{
    constexpr int WN  = BN / 4;        // per-wave N
    constexpr int HN  = WN / 2;        // per-wave N-half
    constexpr int NJQ = WN / 32;       // B frags per half (2 or 1)
    constexpr int LBH = NJQ;           // gld_lds per B-half stage (2 or 1)
    constexpr int NBU = BN / 64;       // B stage units
    constexpr int ABUF = 256 * 64;
    constexpr int BBUF = BN * 64;
    __shared__ __align__(16) unsigned short As[2 * ABUF];
    __shared__ __align__(16) unsigned short Bs[2 * BBUF];

    const int t = threadIdx.x;
    const int l = t & 63, w = t >> 6;
    const int l15 = l & 15, lg = l >> 4;
    const int wr = w >> 2, wc = w & 3;
    const int x7 = l15 & 7;
    const int cc0 = ((lg) ^ x7) << 3;
    const int cc1 = ((4 | lg) ^ x7) << 3;

    // bijective XCD-aware block swizzle (m204)
    const int nwg = (int)gridDim.x;
    const int orig = (int)blockIdx.x;
    const int q8 = nwg >> 3, r8 = nwg & 7;
    const int xcd = orig & 7, lid = orig >> 3;
    const int wg = (xcd < r8 ? xcd * (q8 + 1) : r8 * (q8 + 1) + (xcd - r8) * q8) + lid;
    const int m0 = (wg & 15) * 256;
    const int n0 = (wg >> 4) * BN;

    // staging: thread t fills 16B at LDS (lrow = unit*64 + (t>>3), chunk t&7);
    // global source column pre-swizzled to match read-side XOR (rule #21).
    const int tr = t >> 3;
    const int scol = ((t & 7) ^ (tr & 7)) << 3;
    const unsigned short* pA[4];
    #pragma unroll
    for (int u = 0; u < 4; ++u) {
        const int lrow = u * 64 + tr;
        const int g = ((lrow >> 6) & 1) * 128 + (lrow >> 7) * 64 + (lrow & 63);
        pA[u] = A + (size_t)(m0 + g) * K + scol;
    }
    const unsigned short* pB[NBU];
    #pragma unroll
    for (int u = 0; u < NBU; ++u) {
        const int lrow = u * 64 + tr;
        const int h = lrow / (BN / 2), rem = lrow % (BN / 2);
        const int g = (rem / HN) * WN + h * HN + (rem % HN);
        pB[u] = B + (size_t)(n0 + g) * K + scol;
    }

    f32x4 acc[2][2][4][NJQ] = {};
    s16x8 aF[4][2];
    s16x8 bF[2][NJQ][2];

    const int NT = K / 64;

    // prologue: tile 0 into buf0, issue order A0,B0,A1,B1; retire A0,B0.
    GLD_LDS16(pA[0], &As[0 * 4096 + t * 8]);
    GLD_LDS16(pA[1], &As[1 * 4096 + t * 8]);
    #pragma unroll
    for (int u = 0; u < NBU / 2; ++u) GLD_LDS16(pB[u], &Bs[u * 4096 + t * 8]);
    GLD_LDS16(pA[2], &As[2 * 4096 + t * 8]);
    GLD_LDS16(pA[3], &As[3 * 4096 + t * 8]);
    #pragma unroll
    for (int u = NBU / 2; u < NBU; ++u) GLD_LDS16(pB[u], &Bs[u * 4096 + t * 8]);
    waitvm<2 + LBH>();
    __builtin_amdgcn_s_barrier();

    for (int kt = 0; kt < NT; ++kt) {
        const int rb  = (kt & 1) ? ABUF : 0;
        const int rbB = (kt & 1) ? BBUF : 0;
        const int wb  = ABUF - rb;
        const int wbB = BBUF - rbB;
        const int knext = (kt + 1 < NT ? kt + 1 : kt) * 64;

        // ---- phase 0: quadrant (M0,N0); stage A0(t+1); vmcnt(2) ----
        #pragma unroll
        for (int i = 0; i < 4; ++i) {
            const int lr = wr * 64 + i * 16 + l15;
            aF[i][0] = *(const s16x8*)&As[rb + lr * 64 + cc0];
            aF[i][1] = *(const s16x8*)&As[rb + lr * 64 + cc1];
        }
        #pragma unroll
        for (int j = 0; j < NJQ; ++j) {
            const int lr = wc * HN + j * 16 + l15;
            bF[0][j][0] = *(const s16x8*)&Bs[rbB + lr * 64 + cc0];
            bF[0][j][1] = *(const s16x8*)&Bs[rbB + lr * 64 + cc1];
        }
        GLD_LDS16(pA[0] + knext, &As[wb + 0 * 4096 + t * 8]);
        GLD_LDS16(pA[1] + knext, &As[wb + 1 * 4096 + t * 8]);
        if constexpr (NJQ == 2) asm volatile("s_waitcnt lgkmcnt(8)" ::: "memory");
        __builtin_amdgcn_s_barrier();
        asm volatile("s_waitcnt lgkmcnt(0)" ::: "memory");
        __builtin_amdgcn_sched_barrier(0);
        __builtin_amdgcn_s_setprio(1);
        #pragma unroll
        for (int kk = 0; kk < 2; ++kk)
            #pragma unroll
            for (int i = 0; i < 4; ++i)
                #pragma unroll
                for (int j = 0; j < NJQ; ++j)
                    acc[0][0][i][j] = mfma16(aF[i][kk], bF[0][j][kk], acc[0][0][i][j]);
        __builtin_amdgcn_s_setprio(0);
        __builtin_amdgcn_sched_barrier(0);
        waitvm<2>();                       // retires A1,B1 of current tile
        __builtin_amdgcn_s_barrier();

        // ---- phase 1: quadrant (M0,N1); stage B0(t+1) ----
        #pragma unroll
        for (int j = 0; j < NJQ; ++j) {
            const int lr = (BN / 2) + wc * HN + j * 16 + l15;
            bF[1][j][0] = *(const s16x8*)&Bs[rbB + lr * 64 + cc0];
            bF[1][j][1] = *(const s16x8*)&Bs[rbB + lr * 64 + cc1];
        }
        #pragma unroll
        for (int u = 0; u < NBU / 2; ++u)
            GLD_LDS16(pB[u] + knext, &Bs[wbB + u * 4096 + t * 8]);
        __builtin_amdgcn_s_barrier();
        asm volatile("s_waitcnt lgkmcnt(0)" ::: "memory");
        __builtin_amdgcn_sched_barrier(0);
        __builtin_amdgcn_s_setprio(1);
        #pragma unroll
        for (int kk = 0; kk < 2; ++kk)
            #pragma unroll
            for (int i = 0; i < 4; ++i)
                #pragma unroll
                for (int j = 0; j < NJQ; ++j)
                    acc[0][1][i][j] = mfma16(aF[i][kk], bF[1][j][kk], acc[0][1][i][j]);
        __builtin_amdgcn_s_setprio(0);
        __builtin_amdgcn_sched_barrier(0);
        __builtin_amdgcn_s_barrier();

        // ---- phase 2: quadrant (M1,N0); stage A1(t+1) ----
        #pragma unroll
        for (int i = 0; i < 4; ++i) {
            const int lr = 128 + wr * 64 + i * 16 + l15;
            aF[i][0] = *(const s16x8*)&As[rb + lr * 64 + cc0];
            aF[i][1] = *(const s16x8*)&As[rb + lr * 64 + cc1];
        }
        GLD_LDS16(pA[2] + knext, &As[wb + 2 * 4096 + t * 8]);
        GLD_LDS16(pA[3] + knext, &As[wb + 3 * 4096 + t * 8]);
        __builtin_amdgcn_s_barrier();
        asm volatile("s_waitcnt lgkmcnt(0)" ::: "memory");
        __builtin_amdgcn_sched_barrier(0);
        __builtin_amdgcn_s_setprio(1);
        #pragma unroll
        for (int kk = 0; kk < 2; ++kk)
            #pragma unroll
            for (int i = 0; i < 4; ++i)
                #pragma unroll
                for (int j = 0; j < NJQ; ++j)
                    acc[1][0][i][j] = mfma16(aF[i][kk], bF[0][j][kk], acc[1][0][i][j]);
        __builtin_amdgcn_s_setprio(0);
        __builtin_amdgcn_sched_barrier(0);
        __builtin_amdgcn_s_barrier();

        // ---- phase 3: quadrant (M1,N1); stage B1(t+1); vmcnt(2+LBH) ----
        #pragma unroll
        for (int u = NBU / 2; u < NBU; ++u)
            GLD_LDS16(pB[u] + knext, &Bs[wbB + u * 4096 + t * 8]);
        __builtin_amdgcn_s_barrier();
        __builtin_amdgcn_s_setprio(1);
        #pragma unroll
        for (int kk = 0; kk < 2; ++kk)
            #pragma unroll
            for (int i = 0; i < 4; ++i)
                #pragma unroll
                for (int j = 0; j < NJQ; ++j)
                    acc[1][1][i][j] = mfma16(aF[i][kk], bF[1][j][kk], acc[1][1][i][j]);
        __builtin_amdgcn_s_setprio(0);
        __builtin_amdgcn_sched_barrier(0);
        waitvm<2 + LBH>();                 // retires A0,B0 of next tile
        __builtin_amdgcn_s_barrier();
    }

    // ---------------- epilogue ----------------
    #pragma unroll
    for (int qm = 0; qm < 2; ++qm)
        #pragma unroll
        for (int i = 0; i < 4; ++i)
            #pragma unroll
            for (int r = 0; r < 4; ++r) {
                const int row = m0 + wr * 128 + qm * 64 + i * 16 + lg * 4 + r;
                const size_t rbase = (size_t)row * N;
                #pragma unroll
                for (int qn = 0; qn < 2; ++qn)
                    #pragma unroll
                    for (int j = 0; j < NJQ; ++j) {
                        const int col = n0 + wc * WN + qn * HN + j * 16 + l15;
                        float v = acc[qm][qn][i][j][r];
                        if constexpr (EPI == 0) {
                            ((unsigned short*)Cv)[rbase + col] = f2b(v);
                        } else if constexpr (EPI == 1) {
                            ((float*)Cv)[rbase + col] = v + ADD[rbase + col];
                        } else {
                            unsigned short* Cb = (unsigned short*)Cv;
                            float y = b2f(Cb[rbase + col]);
                            float sg = v / (1.0f + expf(-v));
                            Cb[rbase + col] = f2b(sg * y);
                        }
                    }
            }
}

// ---------------- RoPE table: [S][32] of (cos, sin) ----------------
__global__ void rope_tab_k(float2* __restrict__ tab) {
    int i = blockIdx.x * 256 + threadIdx.x;
    if (i >= 4096 * 32) return;
    int s = i >> 5, d = i & 31;
    float inv = exp2f(-(float)d * (13.287712379549449f / 32.0f));
    float fr = (float)s * inv;
    float sv, cv;
    sincosf(fr, &sv, &cv);
    tab[i] = make_float2(cv, sv);
}

// ---------------- RoPE apply (in-place on qkv, q heads + k heads) ----------------
__global__ void rope_apply_k(unsigned short* __restrict__ qkv, const float2* __restrict__ tab) {
    int i = blockIdx.x * 256 + threadIdx.x;
    if (i >= 4096 * 40 * 4) return;
    int dg = i & 3;
    int rest = i >> 2;
    int head = rest % 40;
    int s = rest / 40;
    int off = head < 32 ? head * 64 : 2048 + (head - 32) * 64;
    unsigned short* p = qkv + (size_t)s * 3072 + off + dg * 8;
    s16x8 x1 = *(const s16x8*)p;
    s16x8 x2 = *(const s16x8*)(p + 32);
    const float2* tb = tab + s * 32 + dg * 8;
    s16x8 o1, o2;
    #pragma unroll
    for (int j = 0; j < 8; ++j) {
        float2 cs = tb[j];
        float a = b2f((unsigned short)x1[j]);
        float b = b2f((unsigned short)x2[j]);
        o1[j] = (short)f2b(a * cs.x - b * cs.y);
        o2[j] = (short)f2b(b * cs.x + a * cs.y);
    }
    *(s16x8*)p = o1;
    *(s16x8*)(p + 32) = o2;
}

// ---------------- Sliding-window attention, flash-style ----------------
__global__ __launch_bounds__(256) void attn_swa(
    const unsigned short* __restrict__ qkv,
    unsigned short* __restrict__ out)
{
    constexpr int LDQ = 3072;
    const int qb = blockIdx.x;
    const int h = blockIdx.y;
    const int kvh = h >> 2;
    const int q0 = qb * 64;
    const int t = threadIdx.x, l = t & 63, w = t >> 6;
    const int l15 = l & 15, lg = l >> 4;

    __shared__ unsigned short Kl[64 * 64];
    __shared__ unsigned short Vt[64 * 72];
    __shared__ unsigned short Pl[4 * 16 * 72];

    s16x8 qf[2];
    {
        const unsigned short* qp = qkv + (size_t)(q0 + w * 16 + l15) * LDQ + h * 64 + lg * 8;
        qf[0] = *(const s16x8*)(qp);
        qf[1] = *(const s16x8*)(qp + 32);
    }
    float m_run[4] = {-1e30f, -1e30f, -1e30f, -1e30f};
    float l_run[4] = {0.f, 0.f, 0.f, 0.f};
    f32x4 o[4] = {};

    const float SC = 0.0625f * 1.4426950408889634f;
    const int kt_lo = qb >= 8 ? qb - 8 : 0;

    for (int kt = kt_lo; kt <= qb; ++kt) {
        const int ks = kt * 64;
        __syncthreads();
        {
            const unsigned short* kg = qkv + (size_t)(ks + (t >> 3)) * LDQ + 2048 + kvh * 64 + (t & 7) * 8;
            GLD_LDS16(kg, Kl + t * 8);
            GLD_LDS16(kg + (size_t)32 * LDQ, Kl + t * 8 + 2048);
        }
        {
            const unsigned short* vg = qkv + (size_t)(ks + l) * LDQ + 2560 + kvh * 64 + w * 16;
            s16x8 v0 = *(const s16x8*)vg;
            s16x8 v1 = *(const s16x8*)(vg + 8);
            #pragma unroll
            for (int j = 0; j < 8; ++j) Vt[(w * 16 + j) * 72 + l] = (unsigned short)v0[j];
            #pragma unroll
            for (int j = 0; j < 8; ++j) Vt[(w * 16 + 8 + j) * 72 + l] = (unsigned short)v1[j];
        }
        __syncthreads();

        f32x4 sf[4] = {};
        #pragma unroll
        for (int kf = 0; kf < 4; ++kf) {
            #pragma unroll
            for (int kk = 0; kk < 2; ++kk) {
                s16x8 kb = *(const s16x8*)(Kl + (kf * 16 + l15) * 64 + kk * 32 + lg * 8);
                sf[kf] = mfma16(qf[kk], kb, sf[kf]);
            }
        }

        float tmax[4];
        #pragma unroll
        for (int r = 0; r < 4; ++r) {
            int qrow = q0 + w * 16 + lg * 4 + r;
            float mx = -1e30f;
            #pragma unroll
            for (int kf = 0; kf < 4; ++kf) {
                int key = ks + kf * 16 + l15;
                bool valid = (key <= qrow) && (qrow - key < 512);
                if (valid) mx = fmaxf(mx, sf[kf][r]);
            }
            #pragma unroll
            for (int d2 = 1; d2 < 16; d2 <<= 1) mx = fmaxf(mx, __shfl_xor(mx, d2));
            tmax[r] = mx;
        }

        float alpha[4], rsum[4];
        #pragma unroll
        for (int r = 0; r < 4; ++r) {
            float mnew = fmaxf(m_run[r], tmax[r]);
            alpha[r] = exp2f((m_run[r] - mnew) * SC);
            m_run[r] = mnew;
            rsum[r] = 0.f;
        }

        unsigned short* Pw = Pl + w * (16 * 72);
        #pragma unroll
        for (int kf = 0; kf < 4; ++kf) {
            #pragma unroll
            for (int r = 0; r < 4; ++r) {
                int qrow = q0 + w * 16 + lg * 4 + r;
                int key = ks + kf * 16 + l15;
                bool valid = (key <= qrow) && (qrow - key < 512);
                float p = valid ? exp2f((sf[kf][r] - m_run[r]) * SC) : 0.f;
                rsum[r] += p;
                Pw[(lg * 4 + r) * 72 + kf * 16 + l15] = f2b(p);
            }
        }
        #pragma unroll
        for (int r = 0; r < 4; ++r) {
            #pragma unroll
            for (int d2 = 1; d2 < 16; d2 <<= 1) rsum[r] += __shfl_xor(rsum[r], d2);
            l_run[r] = l_run[r] * alpha[r] + rsum[r];
        }
        #pragma unroll
        for (int hf = 0; hf < 4; ++hf)
            #pragma unroll
            for (int r = 0; r < 4; ++r) o[hf][r] *= alpha[r];

        asm volatile("s_waitcnt lgkmcnt(0)" ::: "memory");
        __builtin_amdgcn_sched_barrier(0);

        #pragma unroll
        for (int kk2 = 0; kk2 < 2; ++kk2) {
            s16x8 pa = *(const s16x8*)(Pw + l15 * 72 + kk2 * 32 + lg * 8);
            #pragma unroll
            for (int hf = 0; hf < 4; ++hf) {
                s16x8 vb = *(const s16x8*)(Vt + (hf * 16 + l15) * 72 + kk2 * 32 + lg * 8);
                o[hf] = mfma16(pa, vb, o[hf]);
            }
        }
    }

    #pragma unroll
    for (int r = 0; r < 4; ++r) {
        int qrow = q0 + w * 16 + lg * 4 + r;
        float invl = 1.0f / l_run[r];
        unsigned short* orow = out + (size_t)qrow * 2048 + h * 64;
        #pragma unroll
        for (int hf = 0; hf < 4; ++hf)
            orow[hf * 16 + l15] = f2b(o[hf][r] * invl);
    }
}

extern "C" void kernel_launch(void* const* d_in, const int* in_sizes, int n_in,
                              void* d_out, int out_size, void* d_ws, size_t ws_size,
                              hipStream_t stream)
{
    const float* hidden = (const float*)d_in[0];
    const float* w_mix  = (const float*)d_in[1];
    const float* wq     = (const float*)d_in[2];
    const float* wk     = (const float*)d_in[3];
    const float* wv     = (const float*)d_in[4];
    const float* wo     = (const float*)d_in[5];
    const float* w_mlp  = (const float*)d_in[6];
    const float* wg     = (const float*)d_in[7];
    const float* wd     = (const float*)d_in[8];
    float* out = (float*)d_out;

    char* ws = (char*)d_ws;
    size_t off = 0;
    auto alloc = [&](size_t bytes) {
        char* p = ws + off;
        off += (bytes + 255) & ~(size_t)255;
        return p;
    };
    unsigned short* Wt   = (unsigned short*)alloc((size_t)11264 * 2048 * 2);
    unsigned short* xn   = (unsigned short*)alloc((size_t)4096 * 2048 * 2);
    unsigned short* qkv  = (unsigned short*)alloc((size_t)4096 * 3072 * 2);
    float2*         rtab = (float2*)alloc((size_t)4096 * 32 * 8);
    unsigned short* attn = (unsigned short*)alloc((size_t)4096 * 2048 * 2);
    float*          hbuf = (float*)alloc((size_t)4096 * 2048 * 4);
    unsigned short* act  = (unsigned short*)alloc((size_t)4096 * 5632 * 2);

    // 1. x = rmsnorm(hidden) -> bf16
    rmsnorm_bf16<<<4096, 256, 0, stream>>>(hidden, w_mix, xn);

    // 2. W^T for q,k,v concatenated
    transpose_to_bf16<<<dim3(64, 64), 256, 0, stream>>>(wq, Wt, 2048, 2048);
    transpose_to_bf16<<<dim3(16, 64), 256, 0, stream>>>(wk, Wt + (size_t)2048 * 2048, 2048, 512);
    transpose_to_bf16<<<dim3(16, 64), 256, 0, stream>>>(wv, Wt + (size_t)2560 * 2048, 2048, 512);

    // 3. qkv = x @ [wq|wk|wv]   (N=3072) 256x256 tiles -> 192 blocks
    gemmq<256, 0><<<192, 512, 0, stream>>>(xn, Wt, qkv, nullptr, 3072, 2048);

    // 4. RoPE
    rope_tab_k<<<(4096 * 32 + 255) / 256, 256, 0, stream>>>(rtab);
    rope_apply_k<<<(4096 * 40 * 4 + 255) / 256, 256, 0, stream>>>(qkv, rtab);

    // 5. sliding-window attention
    attn_swa<<<dim3(64, 32), 256, 0, stream>>>(qkv, attn);

    // 6. h = hidden + attn @ wo   (N=2048) 256x128 tiles -> 256 blocks
    transpose_to_bf16<<<dim3(64, 64), 256, 0, stream>>>(wo, Wt, 2048, 2048);
    gemmq<128, 1><<<256, 512, 0, stream>>>(attn, Wt, hbuf, hidden, 2048, 2048);

    // 7. xn2 = rmsnorm(h)
    rmsnorm_bf16<<<4096, 256, 0, stream>>>(hbuf, w_mlp, xn);

    // 8. MLP: act = y; act = silu(gate) * act   (N=5632) 256x256 tiles -> 352 blocks
    transpose_to_bf16<<<dim3(352, 64), 256, 0, stream>>>(wg, Wt, 2048, 11264);
    gemmq<256, 0><<<352, 512, 0, stream>>>(xn, Wt + (size_t)5632 * 2048, act, nullptr, 5632, 2048);
    gemmq<256, 2><<<352, 512, 0, stream>>>(xn, Wt, act, nullptr, 5632, 2048);

    // 9. out = h + act @ w_down   (N=2048, K=5632) 256x128 tiles -> 256 blocks
    transpose_to_bf16<<<dim3(64, 176), 256, 0, stream>>>(wd, Wt, 5632, 2048);
    gemmq<128, 1><<<256, 512, 0, stream>>>(act, Wt, out, hbuf, 2048, 5632);
}

// Round 6
// 551.795 us; speedup vs baseline: 1.3760x; 1.1561x over previous
//
#include <hip/hip_runtime.h>
#include <stdint.h>

typedef __attribute__((ext_vector_type(8))) short s16x8;
typedef __attribute__((ext_vector_type(4))) float f32x4;

#define GLD_LDS16(gp, lp) __builtin_amdgcn_global_load_lds( \
    (__attribute__((address_space(1))) void*)(void*)(gp), \
    (__attribute__((address_space(3))) void*)(lp), 16, 0, 0)

__device__ __forceinline__ float b2f(unsigned short s) {
    unsigned int u = ((unsigned int)s) << 16;
    return __builtin_bit_cast(float, u);
}
__device__ __forceinline__ unsigned short f2b(float f) {
    unsigned int u = __builtin_bit_cast(unsigned int, f);
    u = (u + 0x7FFFu + ((u >> 16) & 1u)) >> 16;
    return (unsigned short)u;
}
__device__ __forceinline__ f32x4 mfma16(s16x8 a, s16x8 b, f32x4 c) {
    return __builtin_amdgcn_mfma_f32_16x16x32_bf16(a, b, c, 0, 0, 0);
}
template <int N> __device__ __forceinline__ void waitvm() {
    if constexpr (N == 3) asm volatile("s_waitcnt vmcnt(3)" ::: "memory");
    else if constexpr (N == 4) asm volatile("s_waitcnt vmcnt(4)" ::: "memory");
    else if constexpr (N == 6) asm volatile("s_waitcnt vmcnt(6)" ::: "memory");
}

// ---------------- RMSNorm (fp32 in -> bf16 out), D = 2048 ----------------
__global__ __launch_bounds__(256) void rmsnorm_bf16(
    const float* __restrict__ x, const float* __restrict__ wgt,
    unsigned short* __restrict__ out)
{
    const int row = blockIdx.x;
    const int t = threadIdx.x;
    const float* xr = x + (size_t)row * 2048;
    float4 a = *(const float4*)(xr + t * 8);
    float4 b = *(const float4*)(xr + t * 8 + 4);
    float ss = a.x*a.x + a.y*a.y + a.z*a.z + a.w*a.w
             + b.x*b.x + b.y*b.y + b.z*b.z + b.w*b.w;
    #pragma unroll
    for (int d = 1; d < 64; d <<= 1) ss += __shfl_xor(ss, d);
    __shared__ float red[4];
    if ((t & 63) == 0) red[t >> 6] = ss;
    __syncthreads();
    float tot = red[0] + red[1] + red[2] + red[3];
    float inv = rsqrtf(tot * (1.0f / 2048.0f) + 1e-5f);
    float vals[8] = {a.x, a.y, a.z, a.w, b.x, b.y, b.z, b.w};
    const float* wr_ = wgt + t * 8;
    s16x8 ov;
    #pragma unroll
    for (int j = 0; j < 8; ++j) ov[j] = (short)f2b(vals[j] * inv * wr_[j]);
    *(s16x8*)(out + (size_t)row * 2048 + t * 8) = ov;
}

// ------------- transpose + convert: in fp32 [K][N] -> out bf16 [N][K] -------------
__global__ __launch_bounds__(256) void transpose_to_bf16(
    const float* __restrict__ in, unsigned short* __restrict__ out, int K, int N)
{
    __shared__ float tile[32][33];
    int n0 = blockIdx.x * 32, k0 = blockIdx.y * 32;
    int r = threadIdx.x >> 5, c = threadIdx.x & 31;
    #pragma unroll
    for (int i = 0; i < 4; ++i)
        tile[r + i * 8][c] = in[(size_t)(k0 + r + i * 8) * N + n0 + c];
    __syncthreads();
    #pragma unroll
    for (int i = 0; i < 4; ++i)
        out[(size_t)(n0 + r + i * 8) * K + k0 + c] = f2b(tile[c][r + i * 8]);
}

// ---------------- 3-phase GEMM: C[4096,N] = A[4096,K] * B[N,K]^T ----------------
// BM=256, BN in {256,128}. 8 waves (2M x 4N), per-wave 128 x (BN/4). BK=64.
// Per K-tile 3 phases: P0 {rd A-M0,B-h0; stage A0'; bar; 16/8 MFMA; vm; bar},
// P1 {rd B-h1; stage all-B'; bar; 16/8 MFMA; vm; bar}, P2 {rd A-M1; stage A1';
// bar; 32/16 MFMA; vm; bar}. NO lgkm drain — compiler emits counted lgkmcnt so
// ds_read return overlaps MFMA issue. In-order vmcnt ledger (stream per tile:
// A0[2],B[4|2],A1[2]): P0-end retires B1 (vm4); P1-end retires A1 (vm6|4);
// P2-end retires A0',B0' (vm4|3). Every load >=3-phase issue-to-wait distance.
// Chunk-XOR LDS swizzle, both-sides (zero conflicts, verified R3/R5).
// EPI 0: C bf16.  EPI 1: C fp32 = acc+ADD.
template <int BN, int EPI>
__global__ __launch_bounds__(512, 2) void gemmq(
    const unsigned short* __restrict__ A,
    const unsigned short* __restrict__ B,
    void* __restrict__ Cv,
    const float* __restrict__ ADD,
    int N, int K)
{
    constexpr int WN  = BN / 4;
    constexpr int HN  = WN / 2;
    constexpr int NJQ = WN / 32;       // 2 (BN=256) or 1 (BN=128)
    constexpr int NBU = BN / 64;       // 4 or 2
    constexpr int ABUF = 256 * 64;
    constexpr int BBUF = BN * 64;
    constexpr int W_P0 = 4;
    constexpr int W_P1 = (BN == 256) ? 6 : 4;
    constexpr int W_P2 = (BN == 256) ? 4 : 3;
    __shared__ __align__(16) unsigned short As[2 * ABUF];
    __shared__ __align__(16) unsigned short Bs[2 * BBUF];

    const int t = threadIdx.x;
    const int l = t & 63, w = t >> 6;
    const int l15 = l & 15, lg = l >> 4;
    const int wr = w >> 2, wc = w & 3;
    const int x7 = l15 & 7;
    const int cc0 = ((lg) ^ x7) << 3;
    const int cc1 = ((4 | lg) ^ x7) << 3;

    // bijective XCD-aware block swizzle (m204)
    const int nwg = (int)gridDim.x;
    const int orig = (int)blockIdx.x;
    const int q8 = nwg >> 3, r8 = nwg & 7;
    const int xcd = orig & 7, lid = orig >> 3;
    const int wg = (xcd < r8 ? xcd * (q8 + 1) : r8 * (q8 + 1) + (xcd - r8) * q8) + lid;
    const int m0 = (wg & 15) * 256;
    const int n0 = (wg >> 4) * BN;

    const int tr = t >> 3;
    const int scol = ((t & 7) ^ (tr & 7)) << 3;
    const unsigned short* pA[4];
    #pragma unroll
    for (int u = 0; u < 4; ++u) {
        const int lrow = u * 64 + tr;
        const int g = ((lrow >> 6) & 1) * 128 + (lrow >> 7) * 64 + (lrow & 63);
        pA[u] = A + (size_t)(m0 + g) * K + scol;
    }
    const unsigned short* pB[NBU];
    #pragma unroll
    for (int u = 0; u < NBU; ++u) {
        const int lrow = u * 64 + tr;
        const int h = lrow / (BN / 2), rem = lrow % (BN / 2);
        const int g = (rem / HN) * WN + h * HN + (rem % HN);
        pB[u] = B + (size_t)(n0 + g) * K + scol;
    }

    f32x4 acc[2][2][4][NJQ] = {};
    s16x8 aF[4][2];
    s16x8 bF[2][NJQ][2];

    const int NT = K / 64;

    // prologue: tile 0 into buf0 in stream order A0, B(all), A1; retire A0+B-h0.
    GLD_LDS16(pA[0], &As[0 * 4096 + t * 8]);
    GLD_LDS16(pA[1], &As[1 * 4096 + t * 8]);
    #pragma unroll
    for (int u = 0; u < NBU; ++u) GLD_LDS16(pB[u], &Bs[u * 4096 + t * 8]);
    GLD_LDS16(pA[2], &As[2 * 4096 + t * 8]);
    GLD_LDS16(pA[3], &As[3 * 4096 + t * 8]);
    waitvm<W_P2>();
    __builtin_amdgcn_s_barrier();

    for (int kt = 0; kt < NT; ++kt) {
        const int rb  = (kt & 1) ? ABUF : 0;
        const int rbB = (kt & 1) ? BBUF : 0;
        const int wb  = ABUF - rb;
        const int wbB = BBUF - rbB;
        const int knext = (kt + 1 < NT ? kt + 1 : kt) * 64;

        // ---- P0: quadrant (M0,N0); stage A0'; vm(W_P0) ----
        #pragma unroll
        for (int i = 0; i < 4; ++i) {
            const int lr = wr * 64 + i * 16 + l15;
            aF[i][0] = *(const s16x8*)&As[rb + lr * 64 + cc0];
            aF[i][1] = *(const s16x8*)&As[rb + lr * 64 + cc1];
        }
        #pragma unroll
        for (int j = 0; j < NJQ; ++j) {
            const int lr = wc * HN + j * 16 + l15;
            bF[0][j][0] = *(const s16x8*)&Bs[rbB + lr * 64 + cc0];
            bF[0][j][1] = *(const s16x8*)&Bs[rbB + lr * 64 + cc1];
        }
        GLD_LDS16(pA[0] + knext, &As[wb + 0 * 4096 + t * 8]);
        GLD_LDS16(pA[1] + knext, &As[wb + 1 * 4096 + t * 8]);
        __builtin_amdgcn_s_barrier();
        __builtin_amdgcn_s_setprio(1);
        #pragma unroll
        for (int kk = 0; kk < 2; ++kk)
            #pragma unroll
            for (int i = 0; i < 4; ++i)
                #pragma unroll
                for (int j = 0; j < NJQ; ++j)
                    acc[0][0][i][j] = mfma16(aF[i][kk], bF[0][j][kk], acc[0][0][i][j]);
        __builtin_amdgcn_s_setprio(0);
        waitvm<W_P0>();
        __builtin_amdgcn_s_barrier();

        // ---- P1: quadrant (M0,N1); stage all B'; vm(W_P1) ----
        #pragma unroll
        for (int j = 0; j < NJQ; ++j) {
            const int lr = (BN / 2) + wc * HN + j * 16 + l15;
            bF[1][j][0] = *(const s16x8*)&Bs[rbB + lr * 64 + cc0];
            bF[1][j][1] = *(const s16x8*)&Bs[rbB + lr * 64 + cc1];
        }
        #pragma unroll
        for (int u = 0; u < NBU; ++u)
            GLD_LDS16(pB[u] + knext, &Bs[wbB + u * 4096 + t * 8]);
        __builtin_amdgcn_s_barrier();
        __builtin_amdgcn_s_setprio(1);
        #pragma unroll
        for (int kk = 0; kk < 2; ++kk)
            #pragma unroll
            for (int i = 0; i < 4; ++i)
                #pragma unroll
                for (int j = 0; j < NJQ; ++j)
                    acc[0][1][i][j] = mfma16(aF[i][kk], bF[1][j][kk], acc[0][1][i][j]);
        __builtin_amdgcn_s_setprio(0);
        waitvm<W_P1>();
        __builtin_amdgcn_s_barrier();

        // ---- P2: quadrants (M1,N0)+(M1,N1); stage A1'; vm(W_P2) ----
        #pragma unroll
        for (int i = 0; i < 4; ++i) {
            const int lr = 128 + wr * 64 + i * 16 + l15;
            aF[i][0] = *(const s16x8*)&As[rb + lr * 64 + cc0];
            aF[i][1] = *(const s16x8*)&As[rb + lr * 64 + cc1];
        }
        GLD_LDS16(pA[2] + knext, &As[wb + 2 * 4096 + t * 8]);
        GLD_LDS16(pA[3] + knext, &As[wb + 3 * 4096 + t * 8]);
        __builtin_amdgcn_s_barrier();
        __builtin_amdgcn_s_setprio(1);
        #pragma unroll
        for (int kk = 0; kk < 2; ++kk)
            #pragma unroll
            for (int i = 0; i < 4; ++i)
                #pragma unroll
                for (int j = 0; j < NJQ; ++j)
                    acc[1][0][i][j] = mfma16(aF[i][kk], bF[0][j][kk], acc[1][0][i][j]);
        #pragma unroll
        for (int kk = 0; kk < 2; ++kk)
            #pragma unroll
            for (int i = 0; i < 4; ++i)
                #pragma unroll
                for (int j = 0; j < NJQ; ++j)
                    acc[1][1][i][j] = mfma16(aF[i][kk], bF[1][j][kk], acc[1][1][i][j]);
        __builtin_amdgcn_s_setprio(0);
        waitvm<W_P2>();
        __builtin_amdgcn_s_barrier();
    }

    #pragma unroll
    for (int qm = 0; qm < 2; ++qm)
        #pragma unroll
        for (int i = 0; i < 4; ++i)
            #pragma unroll
            for (int r = 0; r < 4; ++r) {
                const int row = m0 + wr * 128 + qm * 64 + i * 16 + lg * 4 + r;
                const size_t rbase = (size_t)row * N;
                #pragma unroll
                for (int qn = 0; qn < 2; ++qn)
                    #pragma unroll
                    for (int j = 0; j < NJQ; ++j) {
                        const int col = n0 + wc * WN + qn * HN + j * 16 + l15;
                        float v = acc[qm][qn][i][j][r];
                        if constexpr (EPI == 0) {
                            ((unsigned short*)Cv)[rbase + col] = f2b(v);
                        } else {
                            ((float*)Cv)[rbase + col] = v + ADD[rbase + col];
                        }
                    }
            }
}

// ---------------- Dual-B GLU GEMM: act = silu(A@Bg^T) * (A@By^T) ----------------
// BM=256, per-matrix BN=128. Same 3-phase schedule; B-group = Bg0,By0,Bg1,By1.
// Stream per K-tile: A0[2], Bg0,By0,Bg1,By1, A1[2]. vm(4)@P0 retires Bg1,By1;
// vm(6)@P1 retires A1; vm(4)@P2 retires A0',Bg0',By0'. Epilogue: silu(g)*y in reg.
__global__ __launch_bounds__(512, 2) void gemm_glu(
    const unsigned short* __restrict__ A,
    const unsigned short* __restrict__ Bg,
    const unsigned short* __restrict__ By,
    unsigned short* __restrict__ act,
    int N, int K)
{
    constexpr int ABUF = 256 * 64, BBUF = 128 * 64;
    __shared__ __align__(16) unsigned short As[2 * ABUF];
    __shared__ __align__(16) unsigned short Bgs[2 * BBUF];
    __shared__ __align__(16) unsigned short Bys[2 * BBUF];

    const int t = threadIdx.x;
    const int l = t & 63, w = t >> 6;
    const int l15 = l & 15, lg = l >> 4;
    const int wr = w >> 2, wc = w & 3;
    const int x7 = l15 & 7;
    const int cc0 = ((lg) ^ x7) << 3;
    const int cc1 = ((4 | lg) ^ x7) << 3;

    const int nwg = (int)gridDim.x;
    const int orig = (int)blockIdx.x;
    const int q8 = nwg >> 3;
    const int xcd = orig & 7, lid = orig >> 3;
    const int wg = xcd * q8 + lid;           // nwg = 704 divisible by 8
    const int m0 = (wg & 15) * 256;
    const int n0 = (wg >> 4) * 128;

    const int tr = t >> 3;
    const int scol = ((t & 7) ^ (tr & 7)) << 3;
    const unsigned short* pA[4];
    #pragma unroll
    for (int u = 0; u < 4; ++u) {
        const int lrow = u * 64 + tr;
        const int g = ((lrow >> 6) & 1) * 128 + (lrow >> 7) * 64 + (lrow & 63);
        pA[u] = A + (size_t)(m0 + g) * K + scol;
    }
    const unsigned short *pG[2], *pY[2];
    #pragma unroll
    for (int u = 0; u < 2; ++u) {
        const int g = (tr >> 4) * 32 + u * 16 + (tr & 15);
        pG[u] = Bg + (size_t)(n0 + g) * K + scol;
        pY[u] = By + (size_t)(n0 + g) * K + scol;
    }

    f32x4 accG[2][2][4] = {};
    f32x4 accY[2][2][4] = {};
    s16x8 aF[4][2];
    s16x8 gF[2][2], yF[2][2];

    const int NT = K / 64;

    GLD_LDS16(pA[0], &As[0 * 4096 + t * 8]);
    GLD_LDS16(pA[1], &As[1 * 4096 + t * 8]);
    GLD_LDS16(pG[0], &Bgs[0 * 4096 + t * 8]);
    GLD_LDS16(pY[0], &Bys[0 * 4096 + t * 8]);
    GLD_LDS16(pG[1], &Bgs[1 * 4096 + t * 8]);
    GLD_LDS16(pY[1], &Bys[1 * 4096 + t * 8]);
    GLD_LDS16(pA[2], &As[2 * 4096 + t * 8]);
    GLD_LDS16(pA[3], &As[3 * 4096 + t * 8]);
    waitvm<4>();
    __builtin_amdgcn_s_barrier();

    for (int kt = 0; kt < NT; ++kt) {
        const int rb  = (kt & 1) ? ABUF : 0;
        const int rbB = (kt & 1) ? BBUF : 0;
        const int wb  = ABUF - rb;
        const int wbB = BBUF - rbB;
        const int knext = (kt + 1 < NT ? kt + 1 : kt) * 64;

        // ---- P0 ----
        #pragma unroll
        for (int i = 0; i < 4; ++i) {
            const int lr = wr * 64 + i * 16 + l15;
            aF[i][0] = *(const s16x8*)&As[rb + lr * 64 + cc0];
            aF[i][1] = *(const s16x8*)&As[rb + lr * 64 + cc1];
        }
        {
            const int lr = wc * 16 + l15;
            gF[0][0] = *(const s16x8*)&Bgs[rbB + lr * 64 + cc0];
            gF[0][1] = *(const s16x8*)&Bgs[rbB + lr * 64 + cc1];
            yF[0][0] = *(const s16x8*)&Bys[rbB + lr * 64 + cc0];
            yF[0][1] = *(const s16x8*)&Bys[rbB + lr * 64 + cc1];
        }
        GLD_LDS16(pA[0] + knext, &As[wb + 0 * 4096 + t * 8]);
        GLD_LDS16(pA[1] + knext, &As[wb + 1 * 4096 + t * 8]);
        __builtin_amdgcn_s_barrier();
        __builtin_amdgcn_s_setprio(1);
        #pragma unroll
        for (int kk = 0; kk < 2; ++kk)
            #pragma unroll
            for (int i = 0; i < 4; ++i) {
                accG[0][0][i] = mfma16(aF[i][kk], gF[0][kk], accG[0][0][i]);
                accY[0][0][i] = mfma16(aF[i][kk], yF[0][kk], accY[0][0][i]);
            }
        __builtin_amdgcn_s_setprio(0);
        waitvm<4>();
        __builtin_amdgcn_s_barrier();

        // ---- P1 ----
        {
            const int lr = 64 + wc * 16 + l15;
            gF[1][0] = *(const s16x8*)&Bgs[rbB + lr * 64 + cc0];
            gF[1][1] = *(const s16x8*)&Bgs[rbB + lr * 64 + cc1];
            yF[1][0] = *(const s16x8*)&Bys[rbB + lr * 64 + cc0];
            yF[1][1] = *(const s16x8*)&Bys[rbB + lr * 64 + cc1];
        }
        GLD_LDS16(pG[0] + knext, &Bgs[wbB + 0 * 4096 + t * 8]);
        GLD_LDS16(pY[0] + knext, &Bys[wbB + 0 * 4096 + t * 8]);
        GLD_LDS16(pG[1] + knext, &Bgs[wbB + 1 * 4096 + t * 8]);
        GLD_LDS16(pY[1] + knext, &Bys[wbB + 1 * 4096 + t * 8]);
        __builtin_amdgcn_s_barrier();
        __builtin_amdgcn_s_setprio(1);
        #pragma unroll
        for (int kk = 0; kk < 2; ++kk)
            #pragma unroll
            for (int i = 0; i < 4; ++i) {
                accG[0][1][i] = mfma16(aF[i][kk], gF[1][kk], accG[0][1][i]);
                accY[0][1][i] = mfma16(aF[i][kk], yF[1][kk], accY[0][1][i]);
            }
        __builtin_amdgcn_s_setprio(0);
        waitvm<6>();
        __builtin_amdgcn_s_barrier();

        // ---- P2 ----
        #pragma unroll
        for (int i = 0; i < 4; ++i) {
            const int lr = 128 + wr * 64 + i * 16 + l15;
            aF[i][0] = *(const s16x8*)&As[rb + lr * 64 + cc0];
            aF[i][1] = *(const s16x8*)&As[rb + lr * 64 + cc1];
        }
        GLD_LDS16(pA[2] + knext, &As[wb + 2 * 4096 + t * 8]);
        GLD_LDS16(pA[3] + knext, &As[wb + 3 * 4096 + t * 8]);
        __builtin_amdgcn_s_barrier();
        __builtin_amdgcn_s_setprio(1);
        #pragma unroll
        for (int kk = 0; kk < 2; ++kk)
            #pragma unroll
            for (int i = 0; i < 4; ++i) {
                accG[1][0][i] = mfma16(aF[i][kk], gF[0][kk], accG[1][0][i]);
                accY[1][0][i] = mfma16(aF[i][kk], yF[0][kk], accY[1][0][i]);
            }
        #pragma unroll
        for (int kk = 0; kk < 2; ++kk)
            #pragma unroll
            for (int i = 0; i < 4; ++i) {
                accG[1][1][i] = mfma16(aF[i][kk], gF[1][kk], accG[1][1][i]);
                accY[1][1][i] = mfma16(aF[i][kk], yF[1][kk], accY[1][1][i]);
            }
        __builtin_amdgcn_s_setprio(0);
        waitvm<4>();
        __builtin_amdgcn_s_barrier();
    }

    #pragma unroll
    for (int qm = 0; qm < 2; ++qm)
        #pragma unroll
        for (int i = 0; i < 4; ++i)
            #pragma unroll
            for (int r = 0; r < 4; ++r) {
                const int row = m0 + wr * 128 + qm * 64 + i * 16 + lg * 4 + r;
                const size_t rbase = (size_t)row * N;
                #pragma unroll
                for (int qn = 0; qn < 2; ++qn) {
                    const int col = n0 + wc * 32 + qn * 16 + l15;
                    float g = accG[qm][qn][i][r];
                    float y = accY[qm][qn][i][r];
                    float sg = g / (1.0f + expf(-g));
                    act[rbase + col] = f2b(sg * y);
                }
            }
}

// ---------------- RoPE table: [S][32] of (cos, sin) ----------------
__global__ void rope_tab_k(float2* __restrict__ tab) {
    int i = blockIdx.x * 256 + threadIdx.x;
    if (i >= 4096 * 32) return;
    int s = i >> 5, d = i & 31;
    float inv = exp2f(-(float)d * (13.287712379549449f / 32.0f));
    float fr = (float)s * inv;
    float sv, cv;
    sincosf(fr, &sv, &cv);
    tab[i] = make_float2(cv, sv);
}

// ---------------- RoPE apply (in-place on qkv, q heads + k heads) ----------------
__global__ void rope_apply_k(unsigned short* __restrict__ qkv, const float2* __restrict__ tab) {
    int i = blockIdx.x * 256 + threadIdx.x;
    if (i >= 4096 * 40 * 4) return;
    int dg = i & 3;
    int rest = i >> 2;
    int head = rest % 40;
    int s = rest / 40;
    int off = head < 32 ? head * 64 : 2048 + (head - 32) * 64;
    unsigned short* p = qkv + (size_t)s * 3072 + off + dg * 8;
    s16x8 x1 = *(const s16x8*)p;
    s16x8 x2 = *(const s16x8*)(p + 32);
    const float2* tb = tab + s * 32 + dg * 8;
    s16x8 o1, o2;
    #pragma unroll
    for (int j = 0; j < 8; ++j) {
        float2 cs = tb[j];
        float a = b2f((unsigned short)x1[j]);
        float b = b2f((unsigned short)x2[j]);
        o1[j] = (short)f2b(a * cs.x - b * cs.y);
        o2[j] = (short)f2b(b * cs.x + a * cs.y);
    }
    *(s16x8*)p = o1;
    *(s16x8*)(p + 32) = o2;
}

// ---------------- Sliding-window attention, flash-style ----------------
__global__ __launch_bounds__(256) void attn_swa(
    const unsigned short* __restrict__ qkv,
    unsigned short* __restrict__ out)
{
    constexpr int LDQ = 3072;
    const int qb = blockIdx.x;
    const int h = blockIdx.y;
    const int kvh = h >> 2;
    const int q0 = qb * 64;
    const int t = threadIdx.x, l = t & 63, w = t >> 6;
    const int l15 = l & 15, lg = l >> 4;

    __shared__ unsigned short Kl[64 * 64];
    __shared__ unsigned short Vt[64 * 72];
    __shared__ unsigned short Pl[4 * 16 * 72];

    s16x8 qf[2];
    {
        const unsigned short* qp = qkv + (size_t)(q0 + w * 16 + l15) * LDQ + h * 64 + lg * 8;
        qf[0] = *(const s16x8*)(qp);
        qf[1] = *(const s16x8*)(qp + 32);
    }
    float m_run[4] = {-1e30f, -1e30f, -1e30f, -1e30f};
    float l_run[4] = {0.f, 0.f, 0.f, 0.f};
    f32x4 o[4] = {};

    const float SC = 0.0625f * 1.4426950408889634f;
    const int kt_lo = qb >= 8 ? qb - 8 : 0;

    for (int kt = kt_lo; kt <= qb; ++kt) {
        const int ks = kt * 64;
        __syncthreads();
        {
            const unsigned short* kg = qkv + (size_t)(ks + (t >> 3)) * LDQ + 2048 + kvh * 64 + (t & 7) * 8;
            GLD_LDS16(kg, Kl + t * 8);
            GLD_LDS16(kg + (size_t)32 * LDQ, Kl + t * 8 + 2048);
        }
        {
            const unsigned short* vg = qkv + (size_t)(ks + l) * LDQ + 2560 + kvh * 64 + w * 16;
            s16x8 v0 = *(const s16x8*)vg;
            s16x8 v1 = *(const s16x8*)(vg + 8);
            #pragma unroll
            for (int j = 0; j < 8; ++j) Vt[(w * 16 + j) * 72 + l] = (unsigned short)v0[j];
            #pragma unroll
            for (int j = 0; j < 8; ++j) Vt[(w * 16 + 8 + j) * 72 + l] = (unsigned short)v1[j];
        }
        __syncthreads();

        f32x4 sf[4] = {};
        #pragma unroll
        for (int kf = 0; kf < 4; ++kf) {
            #pragma unroll
            for (int kk = 0; kk < 2; ++kk) {
                s16x8 kb = *(const s16x8*)(Kl + (kf * 16 + l15) * 64 + kk * 32 + lg * 8);
                sf[kf] = mfma16(qf[kk], kb, sf[kf]);
            }
        }

        float tmax[4];
        #pragma unroll
        for (int r = 0; r < 4; ++r) {
            int qrow = q0 + w * 16 + lg * 4 + r;
            float mx = -1e30f;
            #pragma unroll
            for (int kf = 0; kf < 4; ++kf) {
                int key = ks + kf * 16 + l15;
                bool valid = (key <= qrow) && (qrow - key < 512);
                if (valid) mx = fmaxf(mx, sf[kf][r]);
            }
            #pragma unroll
            for (int d2 = 1; d2 < 16; d2 <<= 1) mx = fmaxf(mx, __shfl_xor(mx, d2));
            tmax[r] = mx;
        }

        float alpha[4], rsum[4];
        #pragma unroll
        for (int r = 0; r < 4; ++r) {
            float mnew = fmaxf(m_run[r], tmax[r]);
            alpha[r] = exp2f((m_run[r] - mnew) * SC);
            m_run[r] = mnew;
            rsum[r] = 0.f;
        }

        unsigned short* Pw = Pl + w * (16 * 72);
        #pragma unroll
        for (int kf = 0; kf < 4; ++kf) {
            #pragma unroll
            for (int r = 0; r < 4; ++r) {
                int qrow = q0 + w * 16 + lg * 4 + r;
                int key = ks + kf * 16 + l15;
                bool valid = (key <= qrow) && (qrow - key < 512);
                float p = valid ? exp2f((sf[kf][r] - m_run[r]) * SC) : 0.f;
                rsum[r] += p;
                Pw[(lg * 4 + r) * 72 + kf * 16 + l15] = f2b(p);
            }
        }
        #pragma unroll
        for (int r = 0; r < 4; ++r) {
            #pragma unroll
            for (int d2 = 1; d2 < 16; d2 <<= 1) rsum[r] += __shfl_xor(rsum[r], d2);
            l_run[r] = l_run[r] * alpha[r] + rsum[r];
        }
        #pragma unroll
        for (int hf = 0; hf < 4; ++hf)
            #pragma unroll
            for (int r = 0; r < 4; ++r) o[hf][r] *= alpha[r];

        asm volatile("s_waitcnt lgkmcnt(0)" ::: "memory");
        __builtin_amdgcn_sched_barrier(0);

        #pragma unroll
        for (int kk2 = 0; kk2 < 2; ++kk2) {
            s16x8 pa = *(const s16x8*)(Pw + l15 * 72 + kk2 * 32 + lg * 8);
            #pragma unroll
            for (int hf = 0; hf < 4; ++hf) {
                s16x8 vb = *(const s16x8*)(Vt + (hf * 16 + l15) * 72 + kk2 * 32 + lg * 8);
                o[hf] = mfma16(pa, vb, o[hf]);
            }
        }
    }

    #pragma unroll
    for (int r = 0; r < 4; ++r) {
        int qrow = q0 + w * 16 + lg * 4 + r;
        float invl = 1.0f / l_run[r];
        unsigned short* orow = out + (size_t)qrow * 2048 + h * 64;
        #pragma unroll
        for (int hf = 0; hf < 4; ++hf)
            orow[hf * 16 + l15] = f2b(o[hf][r] * invl);
    }
}

extern "C" void kernel_launch(void* const* d_in, const int* in_sizes, int n_in,
                              void* d_out, int out_size, void* d_ws, size_t ws_size,
                              hipStream_t stream)
{
    const float* hidden = (const float*)d_in[0];
    const float* w_mix  = (const float*)d_in[1];
    const float* wq     = (const float*)d_in[2];
    const float* wk     = (const float*)d_in[3];
    const float* wv     = (const float*)d_in[4];
    const float* wo     = (const float*)d_in[5];
    const float* w_mlp  = (const float*)d_in[6];
    const float* wg     = (const float*)d_in[7];
    const float* wd     = (const float*)d_in[8];
    float* out = (float*)d_out;

    char* ws = (char*)d_ws;
    size_t off = 0;
    auto alloc = [&](size_t bytes) {
        char* p = ws + off;
        off += (bytes + 255) & ~(size_t)255;
        return p;
    };
    unsigned short* Wt   = (unsigned short*)alloc((size_t)11264 * 2048 * 2);
    unsigned short* xn   = (unsigned short*)alloc((size_t)4096 * 2048 * 2);
    unsigned short* qkv  = (unsigned short*)alloc((size_t)4096 * 3072 * 2);
    float2*         rtab = (float2*)alloc((size_t)4096 * 32 * 8);
    unsigned short* attn = (unsigned short*)alloc((size_t)4096 * 2048 * 2);
    float*          hbuf = (float*)alloc((size_t)4096 * 2048 * 4);
    unsigned short* act  = (unsigned short*)alloc((size_t)4096 * 5632 * 2);

    // 1. x = rmsnorm(hidden) -> bf16
    rmsnorm_bf16<<<4096, 256, 0, stream>>>(hidden, w_mix, xn);

    // 2. W^T for q,k,v concatenated
    transpose_to_bf16<<<dim3(64, 64), 256, 0, stream>>>(wq, Wt, 2048, 2048);
    transpose_to_bf16<<<dim3(16, 64), 256, 0, stream>>>(wk, Wt + (size_t)2048 * 2048, 2048, 512);
    transpose_to_bf16<<<dim3(16, 64), 256, 0, stream>>>(wv, Wt + (size_t)2560 * 2048, 2048, 512);

    // 3. qkv = x @ [wq|wk|wv]   (N=3072) 256x256 tiles -> 192 blocks
    gemmq<256, 0><<<192, 512, 0, stream>>>(xn, Wt, qkv, nullptr, 3072, 2048);

    // 4. RoPE
    rope_tab_k<<<(4096 * 32 + 255) / 256, 256, 0, stream>>>(rtab);
    rope_apply_k<<<(4096 * 40 * 4 + 255) / 256, 256, 0, stream>>>(qkv, rtab);

    // 5. sliding-window attention
    attn_swa<<<dim3(64, 32), 256, 0, stream>>>(qkv, attn);

    // 6. h = hidden + attn @ wo   (N=2048) 256x128 tiles -> 256 blocks
    transpose_to_bf16<<<dim3(64, 64), 256, 0, stream>>>(wo, Wt, 2048, 2048);
    gemmq<128, 1><<<256, 512, 0, stream>>>(attn, Wt, hbuf, hidden, 2048, 2048);

    // 7. xn2 = rmsnorm(h)
    rmsnorm_bf16<<<4096, 256, 0, stream>>>(hbuf, w_mlp, xn);

    // 8. MLP: act = silu(x@wg_gate^T) * (x@wg_y^T)  -- one dual-B kernel, 704 blocks
    transpose_to_bf16<<<dim3(352, 64), 256, 0, stream>>>(wg, Wt, 2048, 11264);
    gemm_glu<<<704, 512, 0, stream>>>(xn, Wt, Wt + (size_t)5632 * 2048, act, 5632, 2048);

    // 9. out = h + act @ w_down   (N=2048, K=5632) 256x128 tiles -> 256 blocks
    transpose_to_bf16<<<dim3(64, 176), 256, 0, stream>>>(wd, Wt, 5632, 2048);
    gemmq<128, 1><<<256, 512, 0, stream>>>(act, Wt, out, hbuf, 2048, 5632);
}

// Round 7
// 550.398 us; speedup vs baseline: 1.3795x; 1.0025x over previous
//
#include <hip/hip_runtime.h>
#include <stdint.h>

typedef __attribute__((ext_vector_type(8))) short s16x8;
typedef __attribute__((ext_vector_type(4))) float f32x4;

#define GLD_LDS16(gp, lp) __builtin_amdgcn_global_load_lds( \
    (__attribute__((address_space(1))) void*)(void*)(gp), \
    (__attribute__((address_space(3))) void*)(lp), 16, 0, 0)

__device__ __forceinline__ float b2f(unsigned short s) {
    unsigned int u = ((unsigned int)s) << 16;
    return __builtin_bit_cast(float, u);
}
__device__ __forceinline__ unsigned short f2b(float f) {
    unsigned int u = __builtin_bit_cast(unsigned int, f);
    u = (u + 0x7FFFu + ((u >> 16) & 1u)) >> 16;
    return (unsigned short)u;
}
__device__ __forceinline__ f32x4 mfma16(s16x8 a, s16x8 b, f32x4 c) {
    return __builtin_amdgcn_mfma_f32_16x16x32_bf16(a, b, c, 0, 0, 0);
}
template <int N> __device__ __forceinline__ void waitvm() {
    if constexpr (N == 3) asm volatile("s_waitcnt vmcnt(3)" ::: "memory");
    else if constexpr (N == 4) asm volatile("s_waitcnt vmcnt(4)" ::: "memory");
}

// ---------------- RMSNorm (fp32 in -> bf16 out), D = 2048 ----------------
__global__ __launch_bounds__(256) void rmsnorm_bf16(
    const float* __restrict__ x, const float* __restrict__ wgt,
    unsigned short* __restrict__ out)
{
    const int row = blockIdx.x;
    const int t = threadIdx.x;
    const float* xr = x + (size_t)row * 2048;
    float4 a = *(const float4*)(xr + t * 8);
    float4 b = *(const float4*)(xr + t * 8 + 4);
    float ss = a.x*a.x + a.y*a.y + a.z*a.z + a.w*a.w
             + b.x*b.x + b.y*b.y + b.z*b.z + b.w*b.w;
    #pragma unroll
    for (int d = 1; d < 64; d <<= 1) ss += __shfl_xor(ss, d);
    __shared__ float red[4];
    if ((t & 63) == 0) red[t >> 6] = ss;
    __syncthreads();
    float tot = red[0] + red[1] + red[2] + red[3];
    float inv = rsqrtf(tot * (1.0f / 2048.0f) + 1e-5f);
    float vals[8] = {a.x, a.y, a.z, a.w, b.x, b.y, b.z, b.w};
    const float* wr_ = wgt + t * 8;
    s16x8 ov;
    #pragma unroll
    for (int j = 0; j < 8; ++j) ov[j] = (short)f2b(vals[j] * inv * wr_[j]);
    *(s16x8*)(out + (size_t)row * 2048 + t * 8) = ov;
}

// ------------- transpose + convert: in fp32 [K][N] -> out bf16 [N][K] -------------
// 64x64 tiles; float4 (16B) loads, short8 (16B) stores. Grid (N/64, K/64).
__global__ __launch_bounds__(256) void transpose_to_bf16(
    const float* __restrict__ in, unsigned short* __restrict__ out, int K, int N)
{
    __shared__ float tile[64][65];
    const int n0 = blockIdx.x * 64, k0 = blockIdx.y * 64;
    const int t = threadIdx.x;
    const int kr = t >> 4, nc = (t & 15) * 4;
    #pragma unroll
    for (int i = 0; i < 4; ++i) {
        float4 v = *(const float4*)(in + (size_t)(k0 + kr + i * 16) * N + n0 + nc);
        tile[nc + 0][kr + i * 16] = v.x;
        tile[nc + 1][kr + i * 16] = v.y;
        tile[nc + 2][kr + i * 16] = v.z;
        tile[nc + 3][kr + i * 16] = v.w;
    }
    __syncthreads();
    const int nr = t >> 3, kc = (t & 7) * 8;
    #pragma unroll
    for (int p = 0; p < 2; ++p) {
        s16x8 o;
        #pragma unroll
        for (int j = 0; j < 8; ++j) o[j] = (short)f2b(tile[nr + p * 32][kc + j]);
        *(s16x8*)(out + (size_t)(n0 + nr + p * 32) * K + k0 + kc) = o;
    }
}

// ---------------- 4-phase GEMM (m201 schedule): C[4096,N] = A[4096,K] * B[N,K]^T ----------------
// BM=256, BN in {256,128}. 8 waves (2M x 4N), per-wave 128 x (BN/4). BK=64.
// 4 quadrant-phases/K-tile: (M0,N0)(M0,N1)(M1,N0)(M1,N1), 16|8 MFMA each.
// Stage one unit-group of tile t+1 per phase, stream order A0',B0',B1',A1'.
// Per phase: {ds_read frags; stage; barrier; setprio+MFMA; [vmcnt]; barrier}.
// In-order vmcnt ledger (stream A0[2],B0[x],B1[x],A1[2]): P1-end retires B1(t),
// P2-end retires A1(t), P3-end none, P4-end retires A0',B0'. All distances >=2 phases.
// NO lgkm drains (compiler emits counted lgkmcnt). Chunk-XOR LDS swizzle both-sides.
// EPI 0: C bf16.  EPI 1: C fp32 = acc+ADD.
template <int BN, int EPI>
__global__ __launch_bounds__(512, 2) void gemmq(
    const unsigned short* __restrict__ A,
    const unsigned short* __restrict__ B,
    void* __restrict__ Cv,
    const float* __restrict__ ADD,
    int N, int K)
{
    constexpr int WN  = BN / 4;
    constexpr int HN  = WN / 2;
    constexpr int NJQ = WN / 32;       // 2 (BN=256) or 1 (BN=128)
    constexpr int NBU = BN / 64;       // 4 or 2
    constexpr int ABUF = 256 * 64;
    constexpr int BBUF = BN * 64;
    constexpr int W1   = 4;
    constexpr int W2   = (BN == 256) ? 4 : 3;
    constexpr int WEND = (BN == 256) ? 4 : 3;
    __shared__ __align__(16) unsigned short As[2 * ABUF];
    __shared__ __align__(16) unsigned short Bs[2 * BBUF];

    const int t = threadIdx.x;
    const int l = t & 63, w = t >> 6;
    const int l15 = l & 15, lg = l >> 4;
    const int wr = w >> 2, wc = w & 3;
    const int x7 = l15 & 7;
    const int cc0 = ((lg) ^ x7) << 3;
    const int cc1 = ((4 | lg) ^ x7) << 3;

    // bijective XCD-aware block swizzle (m204)
    const int nwg = (int)gridDim.x;
    const int orig = (int)blockIdx.x;
    const int q8 = nwg >> 3, r8 = nwg & 7;
    const int xcd = orig & 7, lid = orig >> 3;
    const int wg = (xcd < r8 ? xcd * (q8 + 1) : r8 * (q8 + 1) + (xcd - r8) * q8) + lid;
    const int m0 = (wg & 15) * 256;
    const int n0 = (wg >> 4) * BN;

    const int tr = t >> 3;
    const int scol = ((t & 7) ^ (tr & 7)) << 3;
    const unsigned short* pA[4];
    #pragma unroll
    for (int u = 0; u < 4; ++u) {
        const int lrow = u * 64 + tr;
        const int g = ((lrow >> 6) & 1) * 128 + (lrow >> 7) * 64 + (lrow & 63);
        pA[u] = A + (size_t)(m0 + g) * K + scol;
    }
    const unsigned short* pB[NBU];
    #pragma unroll
    for (int u = 0; u < NBU; ++u) {
        const int lrow = u * 64 + tr;
        const int h = lrow / (BN / 2), rem = lrow % (BN / 2);
        const int g = (rem / HN) * WN + h * HN + (rem % HN);
        pB[u] = B + (size_t)(n0 + g) * K + scol;
    }

    f32x4 acc[2][2][4][NJQ] = {};
    s16x8 aF[4][2];
    s16x8 bF[2][NJQ][2];

    const int NT = K / 64;

    // prologue: tile 0 into buf0 in stream order A0,B0,B1,A1; retire A0,B0.
    GLD_LDS16(pA[0], &As[0 * 4096 + t * 8]);
    GLD_LDS16(pA[1], &As[1 * 4096 + t * 8]);
    #pragma unroll
    for (int u = 0; u < NBU; ++u) GLD_LDS16(pB[u], &Bs[u * 4096 + t * 8]);
    GLD_LDS16(pA[2], &As[2 * 4096 + t * 8]);
    GLD_LDS16(pA[3], &As[3 * 4096 + t * 8]);
    waitvm<WEND>();
    __builtin_amdgcn_s_barrier();

    for (int kt = 0; kt < NT; ++kt) {
        const int rb  = (kt & 1) ? ABUF : 0;
        const int rbB = (kt & 1) ? BBUF : 0;
        const int wb  = ABUF - rb;
        const int wbB = BBUF - rbB;
        const int knext = (kt + 1 < NT ? kt + 1 : kt) * 64;

        // ---- P1: (M0,N0); stage A0'; vm(W1) ----
        #pragma unroll
        for (int i = 0; i < 4; ++i) {
            const int lr = wr * 64 + i * 16 + l15;
            aF[i][0] = *(const s16x8*)&As[rb + lr * 64 + cc0];
            aF[i][1] = *(const s16x8*)&As[rb + lr * 64 + cc1];
        }
        #pragma unroll
        for (int j = 0; j < NJQ; ++j) {
            const int lr = wc * HN + j * 16 + l15;
            bF[0][j][0] = *(const s16x8*)&Bs[rbB + lr * 64 + cc0];
            bF[0][j][1] = *(const s16x8*)&Bs[rbB + lr * 64 + cc1];
        }
        GLD_LDS16(pA[0] + knext, &As[wb + 0 * 4096 + t * 8]);
        GLD_LDS16(pA[1] + knext, &As[wb + 1 * 4096 + t * 8]);
        __builtin_amdgcn_s_barrier();
        __builtin_amdgcn_s_setprio(1);
        #pragma unroll
        for (int kk = 0; kk < 2; ++kk)
            #pragma unroll
            for (int i = 0; i < 4; ++i)
                #pragma unroll
                for (int j = 0; j < NJQ; ++j)
                    acc[0][0][i][j] = mfma16(aF[i][kk], bF[0][j][kk], acc[0][0][i][j]);
        __builtin_amdgcn_s_setprio(0);
        waitvm<W1>();
        __builtin_amdgcn_s_barrier();

        // ---- P2: (M0,N1); stage B0'; vm(W2) ----
        #pragma unroll
        for (int j = 0; j < NJQ; ++j) {
            const int lr = (BN / 2) + wc * HN + j * 16 + l15;
            bF[1][j][0] = *(const s16x8*)&Bs[rbB + lr * 64 + cc0];
            bF[1][j][1] = *(const s16x8*)&Bs[rbB + lr * 64 + cc1];
        }
        #pragma unroll
        for (int u = 0; u < NBU / 2; ++u)
            GLD_LDS16(pB[u] + knext, &Bs[wbB + u * 4096 + t * 8]);
        __builtin_amdgcn_s_barrier();
        __builtin_amdgcn_s_setprio(1);
        #pragma unroll
        for (int kk = 0; kk < 2; ++kk)
            #pragma unroll
            for (int i = 0; i < 4; ++i)
                #pragma unroll
                for (int j = 0; j < NJQ; ++j)
                    acc[0][1][i][j] = mfma16(aF[i][kk], bF[1][j][kk], acc[0][1][i][j]);
        __builtin_amdgcn_s_setprio(0);
        waitvm<W2>();
        __builtin_amdgcn_s_barrier();

        // ---- P3: (M1,N0); stage B1'; no vmcnt ----
        #pragma unroll
        for (int i = 0; i < 4; ++i) {
            const int lr = 128 + wr * 64 + i * 16 + l15;
            aF[i][0] = *(const s16x8*)&As[rb + lr * 64 + cc0];
            aF[i][1] = *(const s16x8*)&As[rb + lr * 64 + cc1];
        }
        #pragma unroll
        for (int u = NBU / 2; u < NBU; ++u)
            GLD_LDS16(pB[u] + knext, &Bs[wbB + u * 4096 + t * 8]);
        __builtin_amdgcn_s_barrier();
        __builtin_amdgcn_s_setprio(1);
        #pragma unroll
        for (int kk = 0; kk < 2; ++kk)
            #pragma unroll
            for (int i = 0; i < 4; ++i)
                #pragma unroll
                for (int j = 0; j < NJQ; ++j)
                    acc[1][0][i][j] = mfma16(aF[i][kk], bF[0][j][kk], acc[1][0][i][j]);
        __builtin_amdgcn_s_setprio(0);
        __builtin_amdgcn_s_barrier();

        // ---- P4: (M1,N1); stage A1'; vm(WEND) ----
        GLD_LDS16(pA[2] + knext, &As[wb + 2 * 4096 + t * 8]);
        GLD_LDS16(pA[3] + knext, &As[wb + 3 * 4096 + t * 8]);
        __builtin_amdgcn_s_barrier();
        __builtin_amdgcn_s_setprio(1);
        #pragma unroll
        for (int kk = 0; kk < 2; ++kk)
            #pragma unroll
            for (int i = 0; i < 4; ++i)
                #pragma unroll
                for (int j = 0; j < NJQ; ++j)
                    acc[1][1][i][j] = mfma16(aF[i][kk], bF[1][j][kk], acc[1][1][i][j]);
        __builtin_amdgcn_s_setprio(0);
        waitvm<WEND>();
        __builtin_amdgcn_s_barrier();
    }

    #pragma unroll
    for (int qm = 0; qm < 2; ++qm)
        #pragma unroll
        for (int i = 0; i < 4; ++i)
            #pragma unroll
            for (int r = 0; r < 4; ++r) {
                const int row = m0 + wr * 128 + qm * 64 + i * 16 + lg * 4 + r;
                const size_t rbase = (size_t)row * N;
                #pragma unroll
                for (int qn = 0; qn < 2; ++qn)
                    #pragma unroll
                    for (int j = 0; j < NJQ; ++j) {
                        const int col = n0 + wc * WN + qn * HN + j * 16 + l15;
                        float v = acc[qm][qn][i][j][r];
                        if constexpr (EPI == 0) {
                            ((unsigned short*)Cv)[rbase + col] = f2b(v);
                        } else {
                            ((float*)Cv)[rbase + col] = v + ADD[rbase + col];
                        }
                    }
            }
}

// ---------------- Dual-B GLU GEMM, 4-phase: act = silu(A@Bg^T) * (A@By^T) ----------------
// Stream per K-tile: A0[2], G0+Y0[2], G1+Y1[2], A1[2]. Quadrants (M0,GY0)(M0,GY1)
// (M1,GY0)(M1,GY1), 16 MFMA each. vm(4) at P1/P2/P4-end (ledger as gemmq BN=256).
__global__ __launch_bounds__(512, 2) void gemm_glu(
    const unsigned short* __restrict__ A,
    const unsigned short* __restrict__ Bg,
    const unsigned short* __restrict__ By,
    unsigned short* __restrict__ act,
    int N, int K)
{
    constexpr int ABUF = 256 * 64, BBUF = 128 * 64;
    __shared__ __align__(16) unsigned short As[2 * ABUF];
    __shared__ __align__(16) unsigned short Bgs[2 * BBUF];
    __shared__ __align__(16) unsigned short Bys[2 * BBUF];

    const int t = threadIdx.x;
    const int l = t & 63, w = t >> 6;
    const int l15 = l & 15, lg = l >> 4;
    const int wr = w >> 2, wc = w & 3;
    const int x7 = l15 & 7;
    const int cc0 = ((lg) ^ x7) << 3;
    const int cc1 = ((4 | lg) ^ x7) << 3;

    const int nwg = (int)gridDim.x;
    const int orig = (int)blockIdx.x;
    const int q8 = nwg >> 3;
    const int xcd = orig & 7, lid = orig >> 3;
    const int wg = xcd * q8 + lid;           // nwg = 704 divisible by 8
    const int m0 = (wg & 15) * 256;
    const int n0 = (wg >> 4) * 128;

    const int tr = t >> 3;
    const int scol = ((t & 7) ^ (tr & 7)) << 3;
    const unsigned short* pA[4];
    #pragma unroll
    for (int u = 0; u < 4; ++u) {
        const int lrow = u * 64 + tr;
        const int g = ((lrow >> 6) & 1) * 128 + (lrow >> 7) * 64 + (lrow & 63);
        pA[u] = A + (size_t)(m0 + g) * K + scol;
    }
    const unsigned short *pG[2], *pY[2];
    #pragma unroll
    for (int u = 0; u < 2; ++u) {
        const int g = (tr >> 4) * 32 + u * 16 + (tr & 15);
        pG[u] = Bg + (size_t)(n0 + g) * K + scol;
        pY[u] = By + (size_t)(n0 + g) * K + scol;
    }

    f32x4 accG[2][2][4] = {};
    f32x4 accY[2][2][4] = {};
    s16x8 aF[4][2];
    s16x8 gF[2][2], yF[2][2];

    const int NT = K / 64;

    GLD_LDS16(pA[0], &As[0 * 4096 + t * 8]);
    GLD_LDS16(pA[1], &As[1 * 4096 + t * 8]);
    GLD_LDS16(pG[0], &Bgs[0 * 4096 + t * 8]);
    GLD_LDS16(pY[0], &Bys[0 * 4096 + t * 8]);
    GLD_LDS16(pG[1], &Bgs[1 * 4096 + t * 8]);
    GLD_LDS16(pY[1], &Bys[1 * 4096 + t * 8]);
    GLD_LDS16(pA[2], &As[2 * 4096 + t * 8]);
    GLD_LDS16(pA[3], &As[3 * 4096 + t * 8]);
    waitvm<4>();
    __builtin_amdgcn_s_barrier();

    for (int kt = 0; kt < NT; ++kt) {
        const int rb  = (kt & 1) ? ABUF : 0;
        const int rbB = (kt & 1) ? BBUF : 0;
        const int wb  = ABUF - rb;
        const int wbB = BBUF - rbB;
        const int knext = (kt + 1 < NT ? kt + 1 : kt) * 64;

        // ---- P1: (M0,GY0); stage A0'; vm4 ----
        #pragma unroll
        for (int i = 0; i < 4; ++i) {
            const int lr = wr * 64 + i * 16 + l15;
            aF[i][0] = *(const s16x8*)&As[rb + lr * 64 + cc0];
            aF[i][1] = *(const s16x8*)&As[rb + lr * 64 + cc1];
        }
        {
            const int lr = wc * 16 + l15;
            gF[0][0] = *(const s16x8*)&Bgs[rbB + lr * 64 + cc0];
            gF[0][1] = *(const s16x8*)&Bgs[rbB + lr * 64 + cc1];
            yF[0][0] = *(const s16x8*)&Bys[rbB + lr * 64 + cc0];
            yF[0][1] = *(const s16x8*)&Bys[rbB + lr * 64 + cc1];
        }
        GLD_LDS16(pA[0] + knext, &As[wb + 0 * 4096 + t * 8]);
        GLD_LDS16(pA[1] + knext, &As[wb + 1 * 4096 + t * 8]);
        __builtin_amdgcn_s_barrier();
        __builtin_amdgcn_s_setprio(1);
        #pragma unroll
        for (int kk = 0; kk < 2; ++kk)
            #pragma unroll
            for (int i = 0; i < 4; ++i) {
                accG[0][0][i] = mfma16(aF[i][kk], gF[0][kk], accG[0][0][i]);
                accY[0][0][i] = mfma16(aF[i][kk], yF[0][kk], accY[0][0][i]);
            }
        __builtin_amdgcn_s_setprio(0);
        waitvm<4>();
        __builtin_amdgcn_s_barrier();

        // ---- P2: (M0,GY1); stage G0',Y0'; vm4 ----
        {
            const int lr = 64 + wc * 16 + l15;
            gF[1][0] = *(const s16x8*)&Bgs[rbB + lr * 64 + cc0];
            gF[1][1] = *(const s16x8*)&Bgs[rbB + lr * 64 + cc1];
            yF[1][0] = *(const s16x8*)&Bys[rbB + lr * 64 + cc0];
            yF[1][1] = *(const s16x8*)&Bys[rbB + lr * 64 + cc1];
        }
        GLD_LDS16(pG[0] + knext, &Bgs[wbB + 0 * 4096 + t * 8]);
        GLD_LDS16(pY[0] + knext, &Bys[wbB + 0 * 4096 + t * 8]);
        __builtin_amdgcn_s_barrier();
        __builtin_amdgcn_s_setprio(1);
        #pragma unroll
        for (int kk = 0; kk < 2; ++kk)
            #pragma unroll
            for (int i = 0; i < 4; ++i) {
                accG[0][1][i] = mfma16(aF[i][kk], gF[1][kk], accG[0][1][i]);
                accY[0][1][i] = mfma16(aF[i][kk], yF[1][kk], accY[0][1][i]);
            }
        __builtin_amdgcn_s_setprio(0);
        waitvm<4>();
        __builtin_amdgcn_s_barrier();

        // ---- P3: (M1,GY0); stage G1',Y1'; no vmcnt ----
        #pragma unroll
        for (int i = 0; i < 4; ++i) {
            const int lr = 128 + wr * 64 + i * 16 + l15;
            aF[i][0] = *(const s16x8*)&As[rb + lr * 64 + cc0];
            aF[i][1] = *(const s16x8*)&As[rb + lr * 64 + cc1];
        }
        GLD_LDS16(pG[1] + knext, &Bgs[wbB + 1 * 4096 + t * 8]);
        GLD_LDS16(pY[1] + knext, &Bys[wbB + 1 * 4096 + t * 8]);
        __builtin_amdgcn_s_barrier();
        __builtin_amdgcn_s_setprio(1);
        #pragma unroll
        for (int kk = 0; kk < 2; ++kk)
            #pragma unroll
            for (int i = 0; i < 4; ++i) {
                accG[1][0][i] = mfma16(aF[i][kk], gF[0][kk], accG[1][0][i]);
                accY[1][0][i] = mfma16(aF[i][kk], yF[0][kk], accY[1][0][i]);
            }
        __builtin_amdgcn_s_setprio(0);
        __builtin_amdgcn_s_barrier();

        // ---- P4: (M1,GY1); stage A1'; vm4 ----
        GLD_LDS16(pA[2] + knext, &As[wb + 2 * 4096 + t * 8]);
        GLD_LDS16(pA[3] + knext, &As[wb + 3 * 4096 + t * 8]);
        __builtin_amdgcn_s_barrier();
        __builtin_amdgcn_s_setprio(1);
        #pragma unroll
        for (int kk = 0; kk < 2; ++kk)
            #pragma unroll
            for (int i = 0; i < 4; ++i) {
                accG[1][1][i] = mfma16(aF[i][kk], gF[1][kk], accG[1][1][i]);
                accY[1][1][i] = mfma16(aF[i][kk], yF[1][kk], accY[1][1][i]);
            }
        __builtin_amdgcn_s_setprio(0);
        waitvm<4>();
        __builtin_amdgcn_s_barrier();
    }

    #pragma unroll
    for (int qm = 0; qm < 2; ++qm)
        #pragma unroll
        for (int i = 0; i < 4; ++i)
            #pragma unroll
            for (int r = 0; r < 4; ++r) {
                const int row = m0 + wr * 128 + qm * 64 + i * 16 + lg * 4 + r;
                const size_t rbase = (size_t)row * N;
                #pragma unroll
                for (int qn = 0; qn < 2; ++qn) {
                    const int col = n0 + wc * 32 + qn * 16 + l15;
                    float g = accG[qm][qn][i][r];
                    float y = accY[qm][qn][i][r];
                    float sg = g / (1.0f + expf(-g));
                    act[rbase + col] = f2b(sg * y);
                }
            }
}

// ---------------- RoPE table: [S][32] of (cos, sin) ----------------
__global__ void rope_tab_k(float2* __restrict__ tab) {
    int i = blockIdx.x * 256 + threadIdx.x;
    if (i >= 4096 * 32) return;
    int s = i >> 5, d = i & 31;
    float inv = exp2f(-(float)d * (13.287712379549449f / 32.0f));
    float fr = (float)s * inv;
    float sv, cv;
    sincosf(fr, &sv, &cv);
    tab[i] = make_float2(cv, sv);
}

// ---------------- RoPE apply (in-place on qkv, q heads + k heads) ----------------
__global__ void rope_apply_k(unsigned short* __restrict__ qkv, const float2* __restrict__ tab) {
    int i = blockIdx.x * 256 + threadIdx.x;
    if (i >= 4096 * 40 * 4) return;
    int dg = i & 3;
    int rest = i >> 2;
    int head = rest % 40;
    int s = rest / 40;
    int off = head < 32 ? head * 64 : 2048 + (head - 32) * 64;
    unsigned short* p = qkv + (size_t)s * 3072 + off + dg * 8;
    s16x8 x1 = *(const s16x8*)p;
    s16x8 x2 = *(const s16x8*)(p + 32);
    const float2* tb = tab + s * 32 + dg * 8;
    s16x8 o1, o2;
    #pragma unroll
    for (int j = 0; j < 8; ++j) {
        float2 cs = tb[j];
        float a = b2f((unsigned short)x1[j]);
        float b = b2f((unsigned short)x2[j]);
        o1[j] = (short)f2b(a * cs.x - b * cs.y);
        o2[j] = (short)f2b(b * cs.x + a * cs.y);
    }
    *(s16x8*)p = o1;
    *(s16x8*)(p + 32) = o2;
}

// ---------------- Sliding-window attention, flash-style ----------------
__global__ __launch_bounds__(256) void attn_swa(
    const unsigned short* __restrict__ qkv,
    unsigned short* __restrict__ out)
{
    constexpr int LDQ = 3072;
    const int qb = blockIdx.x;
    const int h = blockIdx.y;
    const int kvh = h >> 2;
    const int q0 = qb * 64;
    const int t = threadIdx.x, l = t & 63, w = t >> 6;
    const int l15 = l & 15, lg = l >> 4;

    __shared__ unsigned short Kl[64 * 64];
    __shared__ unsigned short Vt[64 * 72];
    __shared__ unsigned short Pl[4 * 16 * 72];

    s16x8 qf[2];
    {
        const unsigned short* qp = qkv + (size_t)(q0 + w * 16 + l15) * LDQ + h * 64 + lg * 8;
        qf[0] = *(const s16x8*)(qp);
        qf[1] = *(const s16x8*)(qp + 32);
    }
    float m_run[4] = {-1e30f, -1e30f, -1e30f, -1e30f};
    float l_run[4] = {0.f, 0.f, 0.f, 0.f};
    f32x4 o[4] = {};

    const float SC = 0.0625f * 1.4426950408889634f;
    const int kt_lo = qb >= 8 ? qb - 8 : 0;

    for (int kt = kt_lo; kt <= qb; ++kt) {
        const int ks = kt * 64;
        __syncthreads();
        {
            const unsigned short* kg = qkv + (size_t)(ks + (t >> 3)) * LDQ + 2048 + kvh * 64 + (t & 7) * 8;
            GLD_LDS16(kg, Kl + t * 8);
            GLD_LDS16(kg + (size_t)32 * LDQ, Kl + t * 8 + 2048);
        }
        {
            const unsigned short* vg = qkv + (size_t)(ks + l) * LDQ + 2560 + kvh * 64 + w * 16;
            s16x8 v0 = *(const s16x8*)vg;
            s16x8 v1 = *(const s16x8*)(vg + 8);
            #pragma unroll
            for (int j = 0; j < 8; ++j) Vt[(w * 16 + j) * 72 + l] = (unsigned short)v0[j];
            #pragma unroll
            for (int j = 0; j < 8; ++j) Vt[(w * 16 + 8 + j) * 72 + l] = (unsigned short)v1[j];
        }
        __syncthreads();

        f32x4 sf[4] = {};
        #pragma unroll
        for (int kf = 0; kf < 4; ++kf) {
            #pragma unroll
            for (int kk = 0; kk < 2; ++kk) {
                s16x8 kb = *(const s16x8*)(Kl + (kf * 16 + l15) * 64 + kk * 32 + lg * 8);
                sf[kf] = mfma16(qf[kk], kb, sf[kf]);
            }
        }

        float tmax[4];
        #pragma unroll
        for (int r = 0; r < 4; ++r) {
            int qrow = q0 + w * 16 + lg * 4 + r;
            float mx = -1e30f;
            #pragma unroll
            for (int kf = 0; kf < 4; ++kf) {
                int key = ks + kf * 16 + l15;
                bool valid = (key <= qrow) && (qrow - key < 512);
                if (valid) mx = fmaxf(mx, sf[kf][r]);
            }
            #pragma unroll
            for (int d2 = 1; d2 < 16; d2 <<= 1) mx = fmaxf(mx, __shfl_xor(mx, d2));
            tmax[r] = mx;
        }

        float alpha[4], rsum[4];
        #pragma unroll
        for (int r = 0; r < 4; ++r) {
            float mnew = fmaxf(m_run[r], tmax[r]);
            alpha[r] = exp2f((m_run[r] - mnew) * SC);
            m_run[r] = mnew;
            rsum[r] = 0.f;
        }

        unsigned short* Pw = Pl + w * (16 * 72);
        #pragma unroll
        for (int kf = 0; kf < 4; ++kf) {
            #pragma unroll
            for (int r = 0; r < 4; ++r) {
                int qrow = q0 + w * 16 + lg * 4 + r;
                int key = ks + kf * 16 + l15;
                bool valid = (key <= qrow) && (qrow - key < 512);
                float p = valid ? exp2f((sf[kf][r] - m_run[r]) * SC) : 0.f;
                rsum[r] += p;
                Pw[(lg * 4 + r) * 72 + kf * 16 + l15] = f2b(p);
            }
        }
        #pragma unroll
        for (int r = 0; r < 4; ++r) {
            #pragma unroll
            for (int d2 = 1; d2 < 16; d2 <<= 1) rsum[r] += __shfl_xor(rsum[r], d2);
            l_run[r] = l_run[r] * alpha[r] + rsum[r];
        }
        #pragma unroll
        for (int hf = 0; hf < 4; ++hf)
            #pragma unroll
            for (int r = 0; r < 4; ++r) o[hf][r] *= alpha[r];

        asm volatile("s_waitcnt lgkmcnt(0)" ::: "memory");
        __builtin_amdgcn_sched_barrier(0);

        #pragma unroll
        for (int kk2 = 0; kk2 < 2; ++kk2) {
            s16x8 pa = *(const s16x8*)(Pw + l15 * 72 + kk2 * 32 + lg * 8);
            #pragma unroll
            for (int hf = 0; hf < 4; ++hf) {
                s16x8 vb = *(const s16x8*)(Vt + (hf * 16 + l15) * 72 + kk2 * 32 + lg * 8);
                o[hf] = mfma16(pa, vb, o[hf]);
            }
        }
    }

    #pragma unroll
    for (int r = 0; r < 4; ++r) {
        int qrow = q0 + w * 16 + lg * 4 + r;
        float invl = 1.0f / l_run[r];
        unsigned short* orow = out + (size_t)qrow * 2048 + h * 64;
        #pragma unroll
        for (int hf = 0; hf < 4; ++hf)
            orow[hf * 16 + l15] = f2b(o[hf][r] * invl);
    }
}

extern "C" void kernel_launch(void* const* d_in, const int* in_sizes, int n_in,
                              void* d_out, int out_size, void* d_ws, size_t ws_size,
                              hipStream_t stream)
{
    const float* hidden = (const float*)d_in[0];
    const float* w_mix  = (const float*)d_in[1];
    const float* wq     = (const float*)d_in[2];
    const float* wk     = (const float*)d_in[3];
    const float* wv     = (const float*)d_in[4];
    const float* wo     = (const float*)d_in[5];
    const float* w_mlp  = (const float*)d_in[6];
    const float* wg     = (const float*)d_in[7];
    const float* wd     = (const float*)d_in[8];
    float* out = (float*)d_out;

    char* ws = (char*)d_ws;
    size_t off = 0;
    auto alloc = [&](size_t bytes) {
        char* p = ws + off;
        off += (bytes + 255) & ~(size_t)255;
        return p;
    };
    unsigned short* Wt   = (unsigned short*)alloc((size_t)11264 * 2048 * 2);
    unsigned short* xn   = (unsigned short*)alloc((size_t)4096 * 2048 * 2);
    unsigned short* qkv  = (unsigned short*)alloc((size_t)4096 * 3072 * 2);
    float2*         rtab = (float2*)alloc((size_t)4096 * 32 * 8);
    unsigned short* attn = (unsigned short*)alloc((size_t)4096 * 2048 * 2);
    float*          hbuf = (float*)alloc((size_t)4096 * 2048 * 4);
    unsigned short* act  = (unsigned short*)alloc((size_t)4096 * 5632 * 2);

    // 1. x = rmsnorm(hidden) -> bf16
    rmsnorm_bf16<<<4096, 256, 0, stream>>>(hidden, w_mix, xn);

    // 2. W^T for q,k,v concatenated  (grid = (N/64, K/64))
    transpose_to_bf16<<<dim3(32, 32), 256, 0, stream>>>(wq, Wt, 2048, 2048);
    transpose_to_bf16<<<dim3(8, 32), 256, 0, stream>>>(wk, Wt + (size_t)2048 * 2048, 2048, 512);
    transpose_to_bf16<<<dim3(8, 32), 256, 0, stream>>>(wv, Wt + (size_t)2560 * 2048, 2048, 512);

    // 3. qkv = x @ [wq|wk|wv]   (N=3072) 256x256 tiles -> 192 blocks
    gemmq<256, 0><<<192, 512, 0, stream>>>(xn, Wt, qkv, nullptr, 3072, 2048);

    // 4. RoPE
    rope_tab_k<<<(4096 * 32 + 255) / 256, 256, 0, stream>>>(rtab);
    rope_apply_k<<<(4096 * 40 * 4 + 255) / 256, 256, 0, stream>>>(qkv, rtab);

    // 5. sliding-window attention
    attn_swa<<<dim3(64, 32), 256, 0, stream>>>(qkv, attn);

    // 6. h = hidden + attn @ wo   (N=2048) 256x128 tiles -> 256 blocks
    transpose_to_bf16<<<dim3(32, 32), 256, 0, stream>>>(wo, Wt, 2048, 2048);
    gemmq<128, 1><<<256, 512, 0, stream>>>(attn, Wt, hbuf, hidden, 2048, 2048);

    // 7. xn2 = rmsnorm(h)
    rmsnorm_bf16<<<4096, 256, 0, stream>>>(hbuf, w_mlp, xn);

    // 8. MLP: act = silu(x@wg_gate^T) * (x@wg_y^T)  -- one dual-B kernel, 704 blocks
    transpose_to_bf16<<<dim3(176, 32), 256, 0, stream>>>(wg, Wt, 2048, 11264);
    gemm_glu<<<704, 512, 0, stream>>>(xn, Wt, Wt + (size_t)5632 * 2048, act, 5632, 2048);

    // 9. out = h + act @ w_down   (N=2048, K=5632) 256x128 tiles -> 256 blocks
    transpose_to_bf16<<<dim3(32, 88), 256, 0, stream>>>(wd, Wt, 5632, 2048);
    gemmq<128, 1><<<256, 512, 0, stream>>>(act, Wt, out, hbuf, 2048, 5632);
}

// Round 8
// 534.086 us; speedup vs baseline: 1.4216x; 1.0305x over previous
//
#include <hip/hip_runtime.h>
#include <stdint.h>

typedef __attribute__((ext_vector_type(8))) short s16x8;
typedef __attribute__((ext_vector_type(4))) float f32x4;

#define GLD_LDS16(gp, lp) __builtin_amdgcn_global_load_lds( \
    (__attribute__((address_space(1))) void*)(void*)(gp), \
    (__attribute__((address_space(3))) void*)(lp), 16, 0, 0)

__device__ __forceinline__ float b2f(unsigned short s) {
    unsigned int u = ((unsigned int)s) << 16;
    return __builtin_bit_cast(float, u);
}
__device__ __forceinline__ unsigned short f2b(float f) {
    unsigned int u = __builtin_bit_cast(unsigned int, f);
    u = (u + 0x7FFFu + ((u >> 16) & 1u)) >> 16;
    return (unsigned short)u;
}
__device__ __forceinline__ f32x4 mfma16(s16x8 a, s16x8 b, f32x4 c) {
    return __builtin_amdgcn_mfma_f32_16x16x32_bf16(a, b, c, 0, 0, 0);
}

// ---------------- RMSNorm (fp32 in -> bf16 out), D = 2048 ----------------
__global__ __launch_bounds__(256) void rmsnorm_bf16(
    const float* __restrict__ x, const float* __restrict__ wgt,
    unsigned short* __restrict__ out)
{
    const int row = blockIdx.x;
    const int t = threadIdx.x;
    const float* xr = x + (size_t)row * 2048;
    float4 a = *(const float4*)(xr + t * 8);
    float4 b = *(const float4*)(xr + t * 8 + 4);
    float ss = a.x*a.x + a.y*a.y + a.z*a.z + a.w*a.w
             + b.x*b.x + b.y*b.y + b.z*b.z + b.w*b.w;
    #pragma unroll
    for (int d = 1; d < 64; d <<= 1) ss += __shfl_xor(ss, d);
    __shared__ float red[4];
    if ((t & 63) == 0) red[t >> 6] = ss;
    __syncthreads();
    float tot = red[0] + red[1] + red[2] + red[3];
    float inv = rsqrtf(tot * (1.0f / 2048.0f) + 1e-5f);
    float vals[8] = {a.x, a.y, a.z, a.w, b.x, b.y, b.z, b.w};
    const float* wr_ = wgt + t * 8;
    s16x8 ov;
    #pragma unroll
    for (int j = 0; j < 8; ++j) ov[j] = (short)f2b(vals[j] * inv * wr_[j]);
    *(s16x8*)(out + (size_t)row * 2048 + t * 8) = ov;
}

// ------------- transpose + convert: in fp32 [K][N] -> out bf16 [N][K] -------------
// 64x64 tiles; float4 (16B) loads, short8 (16B) stores. Grid (N/64, K/64).
__global__ __launch_bounds__(256) void transpose_to_bf16(
    const float* __restrict__ in, unsigned short* __restrict__ out, int K, int N)
{
    __shared__ float tile[64][65];
    const int n0 = blockIdx.x * 64, k0 = blockIdx.y * 64;
    const int t = threadIdx.x;
    const int kr = t >> 4, nc = (t & 15) * 4;
    #pragma unroll
    for (int i = 0; i < 4; ++i) {
        float4 v = *(const float4*)(in + (size_t)(k0 + kr + i * 16) * N + n0 + nc);
        tile[nc + 0][kr + i * 16] = v.x;
        tile[nc + 1][kr + i * 16] = v.y;
        tile[nc + 2][kr + i * 16] = v.z;
        tile[nc + 3][kr + i * 16] = v.w;
    }
    __syncthreads();
    const int nr = t >> 3, kc = (t & 7) * 8;
    #pragma unroll
    for (int p = 0; p < 2; ++p) {
        s16x8 o;
        #pragma unroll
        for (int j = 0; j < 8; ++j) o[j] = (short)f2b(tile[nr + p * 32][kc + j]);
        *(s16x8*)(out + (size_t)(n0 + nr + p * 32) * K + k0 + kc) = o;
    }
}

// ---------------- Minimal-sync GEMM: C[4096,N] = A[4096,K] * B[N,K]^T ----------------
// BM=256, BN in {256,128}. 8 waves (2M x 4N), per-wave 128 x (BN/4). BK=64.
// Per K-tile: straight-line {read A-M0,B0; stage A'(4); MFMA(M0,N0);
// read B1; stage B'(NBU); MFMA(M0,N1); read A-M1; MFMA(M1,N0); MFMA(M1,N1)}
// then ONE vmcnt(0) + ONE raw s_barrier at the tile boundary.
// Rationale: MFMA touches registers only; intra-tile reads hit the read buffer,
// stages hit the write buffer -> only the buffer flip needs sync. No intra-tile
// barriers => waves slip, so one wave's ds_reads overlap another's MFMA (the
// overlap R7's counters proved was missing). Compiler emits counted lgkmcnt.
// Chunk-XOR LDS swizzle both-sides (zero conflicts, verified R3-R7).
// EPI 0: C bf16.  EPI 1: C fp32 = acc+ADD.
template <int BN, int EPI>
__global__ __launch_bounds__(512, 2) void gemmq(
    const unsigned short* __restrict__ A,
    const unsigned short* __restrict__ B,
    void* __restrict__ Cv,
    const float* __restrict__ ADD,
    int N, int K)
{
    constexpr int WN  = BN / 4;
    constexpr int HN  = WN / 2;
    constexpr int NJQ = WN / 32;       // 2 (BN=256) or 1 (BN=128)
    constexpr int NBU = BN / 64;       // 4 or 2
    constexpr int ABUF = 256 * 64;
    constexpr int BBUF = BN * 64;
    __shared__ __align__(16) unsigned short As[2 * ABUF];
    __shared__ __align__(16) unsigned short Bs[2 * BBUF];

    const int t = threadIdx.x;
    const int l = t & 63, w = t >> 6;
    const int l15 = l & 15, lg = l >> 4;
    const int wr = w >> 2, wc = w & 3;
    const int x7 = l15 & 7;
    const int cc0 = ((lg) ^ x7) << 3;
    const int cc1 = ((4 | lg) ^ x7) << 3;

    // bijective XCD-aware block swizzle (m204)
    const int nwg = (int)gridDim.x;
    const int orig = (int)blockIdx.x;
    const int q8 = nwg >> 3, r8 = nwg & 7;
    const int xcd = orig & 7, lid = orig >> 3;
    const int wg = (xcd < r8 ? xcd * (q8 + 1) : r8 * (q8 + 1) + (xcd - r8) * q8) + lid;
    const int m0 = (wg & 15) * 256;
    const int n0 = (wg >> 4) * BN;

    const int tr = t >> 3;
    const int scol = ((t & 7) ^ (tr & 7)) << 3;
    const unsigned short* pA[4];
    #pragma unroll
    for (int u = 0; u < 4; ++u) {
        const int lrow = u * 64 + tr;
        const int g = ((lrow >> 6) & 1) * 128 + (lrow >> 7) * 64 + (lrow & 63);
        pA[u] = A + (size_t)(m0 + g) * K + scol;
    }
    const unsigned short* pB[NBU];
    #pragma unroll
    for (int u = 0; u < NBU; ++u) {
        const int lrow = u * 64 + tr;
        const int h = lrow / (BN / 2), rem = lrow % (BN / 2);
        const int g = (rem / HN) * WN + h * HN + (rem % HN);
        pB[u] = B + (size_t)(n0 + g) * K + scol;
    }

    f32x4 acc[2][2][4][NJQ] = {};
    s16x8 aF[4][2];
    s16x8 bF[2][NJQ][2];

    const int NT = K / 64;

    // prologue: tile 0 into buf0; full drain + barrier.
    #pragma unroll
    for (int u = 0; u < 4; ++u) GLD_LDS16(pA[u], &As[u * 4096 + t * 8]);
    #pragma unroll
    for (int u = 0; u < NBU; ++u) GLD_LDS16(pB[u], &Bs[u * 4096 + t * 8]);
    asm volatile("s_waitcnt vmcnt(0)" ::: "memory");
    __builtin_amdgcn_s_barrier();

    for (int kt = 0; kt < NT; ++kt) {
        const int rb  = (kt & 1) ? ABUF : 0;
        const int rbB = (kt & 1) ? BBUF : 0;
        const int wb  = ABUF - rb;
        const int wbB = BBUF - rbB;
        const int knext = (kt + 1 < NT ? kt + 1 : kt) * 64;

        // ---- phase 1: (M0,N0); stage all A' ----
        #pragma unroll
        for (int i = 0; i < 4; ++i) {
            const int lr = wr * 64 + i * 16 + l15;
            aF[i][0] = *(const s16x8*)&As[rb + lr * 64 + cc0];
            aF[i][1] = *(const s16x8*)&As[rb + lr * 64 + cc1];
        }
        #pragma unroll
        for (int j = 0; j < NJQ; ++j) {
            const int lr = wc * HN + j * 16 + l15;
            bF[0][j][0] = *(const s16x8*)&Bs[rbB + lr * 64 + cc0];
            bF[0][j][1] = *(const s16x8*)&Bs[rbB + lr * 64 + cc1];
        }
        #pragma unroll
        for (int u = 0; u < 4; ++u)
            GLD_LDS16(pA[u] + knext, &As[wb + u * 4096 + t * 8]);
        __builtin_amdgcn_s_setprio(1);
        #pragma unroll
        for (int kk = 0; kk < 2; ++kk)
            #pragma unroll
            for (int i = 0; i < 4; ++i)
                #pragma unroll
                for (int j = 0; j < NJQ; ++j)
                    acc[0][0][i][j] = mfma16(aF[i][kk], bF[0][j][kk], acc[0][0][i][j]);
        __builtin_amdgcn_s_setprio(0);

        // ---- phase 2: (M0,N1); stage all B' ----
        #pragma unroll
        for (int j = 0; j < NJQ; ++j) {
            const int lr = (BN / 2) + wc * HN + j * 16 + l15;
            bF[1][j][0] = *(const s16x8*)&Bs[rbB + lr * 64 + cc0];
            bF[1][j][1] = *(const s16x8*)&Bs[rbB + lr * 64 + cc1];
        }
        #pragma unroll
        for (int u = 0; u < NBU; ++u)
            GLD_LDS16(pB[u] + knext, &Bs[wbB + u * 4096 + t * 8]);
        __builtin_amdgcn_s_setprio(1);
        #pragma unroll
        for (int kk = 0; kk < 2; ++kk)
            #pragma unroll
            for (int i = 0; i < 4; ++i)
                #pragma unroll
                for (int j = 0; j < NJQ; ++j)
                    acc[0][1][i][j] = mfma16(aF[i][kk], bF[1][j][kk], acc[0][1][i][j]);
        __builtin_amdgcn_s_setprio(0);

        // ---- phase 3: (M1,N0) ----
        #pragma unroll
        for (int i = 0; i < 4; ++i) {
            const int lr = 128 + wr * 64 + i * 16 + l15;
            aF[i][0] = *(const s16x8*)&As[rb + lr * 64 + cc0];
            aF[i][1] = *(const s16x8*)&As[rb + lr * 64 + cc1];
        }
        __builtin_amdgcn_s_setprio(1);
        #pragma unroll
        for (int kk = 0; kk < 2; ++kk)
            #pragma unroll
            for (int i = 0; i < 4; ++i)
                #pragma unroll
                for (int j = 0; j < NJQ; ++j)
                    acc[1][0][i][j] = mfma16(aF[i][kk], bF[0][j][kk], acc[1][0][i][j]);
        __builtin_amdgcn_s_setprio(0);

        // ---- phase 4: (M1,N1) ----
        __builtin_amdgcn_s_setprio(1);
        #pragma unroll
        for (int kk = 0; kk < 2; ++kk)
            #pragma unroll
            for (int i = 0; i < 4; ++i)
                #pragma unroll
                for (int j = 0; j < NJQ; ++j)
                    acc[1][1][i][j] = mfma16(aF[i][kk], bF[1][j][kk], acc[1][1][i][j]);
        __builtin_amdgcn_s_setprio(0);

        // ---- tile boundary: the ONLY sync ----
        asm volatile("s_waitcnt vmcnt(0)" ::: "memory");
        __builtin_amdgcn_s_barrier();
    }

    #pragma unroll
    for (int qm = 0; qm < 2; ++qm)
        #pragma unroll
        for (int i = 0; i < 4; ++i)
            #pragma unroll
            for (int r = 0; r < 4; ++r) {
                const int row = m0 + wr * 128 + qm * 64 + i * 16 + lg * 4 + r;
                const size_t rbase = (size_t)row * N;
                #pragma unroll
                for (int qn = 0; qn < 2; ++qn)
                    #pragma unroll
                    for (int j = 0; j < NJQ; ++j) {
                        const int col = n0 + wc * WN + qn * HN + j * 16 + l15;
                        float v = acc[qm][qn][i][j][r];
                        if constexpr (EPI == 0) {
                            ((unsigned short*)Cv)[rbase + col] = f2b(v);
                        } else {
                            ((float*)Cv)[rbase + col] = v + ADD[rbase + col];
                        }
                    }
            }
}

// ---------------- Dual-B GLU GEMM, minimal-sync: act = silu(A@Bg^T) * (A@By^T) ----------------
// Same minimal-sync structure; stages: A'(4) in phase 1, G'/Y'(4) in phase 2.
__global__ __launch_bounds__(512, 2) void gemm_glu(
    const unsigned short* __restrict__ A,
    const unsigned short* __restrict__ Bg,
    const unsigned short* __restrict__ By,
    unsigned short* __restrict__ act,
    int N, int K)
{
    constexpr int ABUF = 256 * 64, BBUF = 128 * 64;
    __shared__ __align__(16) unsigned short As[2 * ABUF];
    __shared__ __align__(16) unsigned short Bgs[2 * BBUF];
    __shared__ __align__(16) unsigned short Bys[2 * BBUF];

    const int t = threadIdx.x;
    const int l = t & 63, w = t >> 6;
    const int l15 = l & 15, lg = l >> 4;
    const int wr = w >> 2, wc = w & 3;
    const int x7 = l15 & 7;
    const int cc0 = ((lg) ^ x7) << 3;
    const int cc1 = ((4 | lg) ^ x7) << 3;

    const int nwg = (int)gridDim.x;
    const int orig = (int)blockIdx.x;
    const int q8 = nwg >> 3;
    const int xcd = orig & 7, lid = orig >> 3;
    const int wg = xcd * q8 + lid;           // nwg = 704 divisible by 8
    const int m0 = (wg & 15) * 256;
    const int n0 = (wg >> 4) * 128;

    const int tr = t >> 3;
    const int scol = ((t & 7) ^ (tr & 7)) << 3;
    const unsigned short* pA[4];
    #pragma unroll
    for (int u = 0; u < 4; ++u) {
        const int lrow = u * 64 + tr;
        const int g = ((lrow >> 6) & 1) * 128 + (lrow >> 7) * 64 + (lrow & 63);
        pA[u] = A + (size_t)(m0 + g) * K + scol;
    }
    const unsigned short *pG[2], *pY[2];
    #pragma unroll
    for (int u = 0; u < 2; ++u) {
        const int g = (tr >> 4) * 32 + u * 16 + (tr & 15);
        pG[u] = Bg + (size_t)(n0 + g) * K + scol;
        pY[u] = By + (size_t)(n0 + g) * K + scol;
    }

    f32x4 accG[2][2][4] = {};
    f32x4 accY[2][2][4] = {};
    s16x8 aF[4][2];
    s16x8 gF[2][2], yF[2][2];

    const int NT = K / 64;

    #pragma unroll
    for (int u = 0; u < 4; ++u) GLD_LDS16(pA[u], &As[u * 4096 + t * 8]);
    GLD_LDS16(pG[0], &Bgs[0 * 4096 + t * 8]);
    GLD_LDS16(pY[0], &Bys[0 * 4096 + t * 8]);
    GLD_LDS16(pG[1], &Bgs[1 * 4096 + t * 8]);
    GLD_LDS16(pY[1], &Bys[1 * 4096 + t * 8]);
    asm volatile("s_waitcnt vmcnt(0)" ::: "memory");
    __builtin_amdgcn_s_barrier();

    for (int kt = 0; kt < NT; ++kt) {
        const int rb  = (kt & 1) ? ABUF : 0;
        const int rbB = (kt & 1) ? BBUF : 0;
        const int wb  = ABUF - rb;
        const int wbB = BBUF - rbB;
        const int knext = (kt + 1 < NT ? kt + 1 : kt) * 64;

        // ---- phase 1: (M0,GY0); stage all A' ----
        #pragma unroll
        for (int i = 0; i < 4; ++i) {
            const int lr = wr * 64 + i * 16 + l15;
            aF[i][0] = *(const s16x8*)&As[rb + lr * 64 + cc0];
            aF[i][1] = *(const s16x8*)&As[rb + lr * 64 + cc1];
        }
        {
            const int lr = wc * 16 + l15;
            gF[0][0] = *(const s16x8*)&Bgs[rbB + lr * 64 + cc0];
            gF[0][1] = *(const s16x8*)&Bgs[rbB + lr * 64 + cc1];
            yF[0][0] = *(const s16x8*)&Bys[rbB + lr * 64 + cc0];
            yF[0][1] = *(const s16x8*)&Bys[rbB + lr * 64 + cc1];
        }
        #pragma unroll
        for (int u = 0; u < 4; ++u)
            GLD_LDS16(pA[u] + knext, &As[wb + u * 4096 + t * 8]);
        __builtin_amdgcn_s_setprio(1);
        #pragma unroll
        for (int kk = 0; kk < 2; ++kk)
            #pragma unroll
            for (int i = 0; i < 4; ++i) {
                accG[0][0][i] = mfma16(aF[i][kk], gF[0][kk], accG[0][0][i]);
                accY[0][0][i] = mfma16(aF[i][kk], yF[0][kk], accY[0][0][i]);
            }
        __builtin_amdgcn_s_setprio(0);

        // ---- phase 2: (M0,GY1); stage all G',Y' ----
        {
            const int lr = 64 + wc * 16 + l15;
            gF[1][0] = *(const s16x8*)&Bgs[rbB + lr * 64 + cc0];
            gF[1][1] = *(const s16x8*)&Bgs[rbB + lr * 64 + cc1];
            yF[1][0] = *(const s16x8*)&Bys[rbB + lr * 64 + cc0];
            yF[1][1] = *(const s16x8*)&Bys[rbB + lr * 64 + cc1];
        }
        GLD_LDS16(pG[0] + knext, &Bgs[wbB + 0 * 4096 + t * 8]);
        GLD_LDS16(pY[0] + knext, &Bys[wbB + 0 * 4096 + t * 8]);
        GLD_LDS16(pG[1] + knext, &Bgs[wbB + 1 * 4096 + t * 8]);
        GLD_LDS16(pY[1] + knext, &Bys[wbB + 1 * 4096 + t * 8]);
        __builtin_amdgcn_s_setprio(1);
        #pragma unroll
        for (int kk = 0; kk < 2; ++kk)
            #pragma unroll
            for (int i = 0; i < 4; ++i) {
                accG[0][1][i] = mfma16(aF[i][kk], gF[1][kk], accG[0][1][i]);
                accY[0][1][i] = mfma16(aF[i][kk], yF[1][kk], accY[0][1][i]);
            }
        __builtin_amdgcn_s_setprio(0);

        // ---- phase 3: (M1,GY0) ----
        #pragma unroll
        for (int i = 0; i < 4; ++i) {
            const int lr = 128 + wr * 64 + i * 16 + l15;
            aF[i][0] = *(const s16x8*)&As[rb + lr * 64 + cc0];
            aF[i][1] = *(const s16x8*)&As[rb + lr * 64 + cc1];
        }
        __builtin_amdgcn_s_setprio(1);
        #pragma unroll
        for (int kk = 0; kk < 2; ++kk)
            #pragma unroll
            for (int i = 0; i < 4; ++i) {
                accG[1][0][i] = mfma16(aF[i][kk], gF[0][kk], accG[1][0][i]);
                accY[1][0][i] = mfma16(aF[i][kk], yF[0][kk], accY[1][0][i]);
            }
        __builtin_amdgcn_s_setprio(0);

        // ---- phase 4: (M1,GY1) ----
        __builtin_amdgcn_s_setprio(1);
        #pragma unroll
        for (int kk = 0; kk < 2; ++kk)
            #pragma unroll
            for (int i = 0; i < 4; ++i) {
                accG[1][1][i] = mfma16(aF[i][kk], gF[1][kk], accG[1][1][i]);
                accY[1][1][i] = mfma16(aF[i][kk], yF[1][kk], accY[1][1][i]);
            }
        __builtin_amdgcn_s_setprio(0);

        // ---- tile boundary: the ONLY sync ----
        asm volatile("s_waitcnt vmcnt(0)" ::: "memory");
        __builtin_amdgcn_s_barrier();
    }

    #pragma unroll
    for (int qm = 0; qm < 2; ++qm)
        #pragma unroll
        for (int i = 0; i < 4; ++i)
            #pragma unroll
            for (int r = 0; r < 4; ++r) {
                const int row = m0 + wr * 128 + qm * 64 + i * 16 + lg * 4 + r;
                const size_t rbase = (size_t)row * N;
                #pragma unroll
                for (int qn = 0; qn < 2; ++qn) {
                    const int col = n0 + wc * 32 + qn * 16 + l15;
                    float g = accG[qm][qn][i][r];
                    float y = accY[qm][qn][i][r];
                    float sg = g / (1.0f + expf(-g));
                    act[rbase + col] = f2b(sg * y);
                }
            }
}

// ---------------- RoPE table: [S][32] of (cos, sin) ----------------
__global__ void rope_tab_k(float2* __restrict__ tab) {
    int i = blockIdx.x * 256 + threadIdx.x;
    if (i >= 4096 * 32) return;
    int s = i >> 5, d = i & 31;
    float inv = exp2f(-(float)d * (13.287712379549449f / 32.0f));
    float fr = (float)s * inv;
    float sv, cv;
    sincosf(fr, &sv, &cv);
    tab[i] = make_float2(cv, sv);
}

// ---------------- RoPE apply (in-place on qkv, q heads + k heads) ----------------
__global__ void rope_apply_k(unsigned short* __restrict__ qkv, const float2* __restrict__ tab) {
    int i = blockIdx.x * 256 + threadIdx.x;
    if (i >= 4096 * 40 * 4) return;
    int dg = i & 3;
    int rest = i >> 2;
    int head = rest % 40;
    int s = rest / 40;
    int off = head < 32 ? head * 64 : 2048 + (head - 32) * 64;
    unsigned short* p = qkv + (size_t)s * 3072 + off + dg * 8;
    s16x8 x1 = *(const s16x8*)p;
    s16x8 x2 = *(const s16x8*)(p + 32);
    const float2* tb = tab + s * 32 + dg * 8;
    s16x8 o1, o2;
    #pragma unroll
    for (int j = 0; j < 8; ++j) {
        float2 cs = tb[j];
        float a = b2f((unsigned short)x1[j]);
        float b = b2f((unsigned short)x2[j]);
        o1[j] = (short)f2b(a * cs.x - b * cs.y);
        o2[j] = (short)f2b(b * cs.x + a * cs.y);
    }
    *(s16x8*)p = o1;
    *(s16x8*)(p + 32) = o2;
}

// ---------------- Sliding-window attention, flash-style ----------------
__global__ __launch_bounds__(256) void attn_swa(
    const unsigned short* __restrict__ qkv,
    unsigned short* __restrict__ out)
{
    constexpr int LDQ = 3072;
    const int qb = blockIdx.x;
    const int h = blockIdx.y;
    const int kvh = h >> 2;
    const int q0 = qb * 64;
    const int t = threadIdx.x, l = t & 63, w = t >> 6;
    const int l15 = l & 15, lg = l >> 4;

    __shared__ unsigned short Kl[64 * 64];
    __shared__ unsigned short Vt[64 * 72];
    __shared__ unsigned short Pl[4 * 16 * 72];

    s16x8 qf[2];
    {
        const unsigned short* qp = qkv + (size_t)(q0 + w * 16 + l15) * LDQ + h * 64 + lg * 8;
        qf[0] = *(const s16x8*)(qp);
        qf[1] = *(const s16x8*)(qp + 32);
    }
    float m_run[4] = {-1e30f, -1e30f, -1e30f, -1e30f};
    float l_run[4] = {0.f, 0.f, 0.f, 0.f};
    f32x4 o[4] = {};

    const float SC = 0.0625f * 1.4426950408889634f;
    const int kt_lo = qb >= 8 ? qb - 8 : 0;

    for (int kt = kt_lo; kt <= qb; ++kt) {
        const int ks = kt * 64;
        __syncthreads();
        {
            const unsigned short* kg = qkv + (size_t)(ks + (t >> 3)) * LDQ + 2048 + kvh * 64 + (t & 7) * 8;
            GLD_LDS16(kg, Kl + t * 8);
            GLD_LDS16(kg + (size_t)32 * LDQ, Kl + t * 8 + 2048);
        }
        {
            const unsigned short* vg = qkv + (size_t)(ks + l) * LDQ + 2560 + kvh * 64 + w * 16;
            s16x8 v0 = *(const s16x8*)vg;
            s16x8 v1 = *(const s16x8*)(vg + 8);
            #pragma unroll
            for (int j = 0; j < 8; ++j) Vt[(w * 16 + j) * 72 + l] = (unsigned short)v0[j];
            #pragma unroll
            for (int j = 0; j < 8; ++j) Vt[(w * 16 + 8 + j) * 72 + l] = (unsigned short)v1[j];
        }
        __syncthreads();

        f32x4 sf[4] = {};
        #pragma unroll
        for (int kf = 0; kf < 4; ++kf) {
            #pragma unroll
            for (int kk = 0; kk < 2; ++kk) {
                s16x8 kb = *(const s16x8*)(Kl + (kf * 16 + l15) * 64 + kk * 32 + lg * 8);
                sf[kf] = mfma16(qf[kk], kb, sf[kf]);
            }
        }

        float tmax[4];
        #pragma unroll
        for (int r = 0; r < 4; ++r) {
            int qrow = q0 + w * 16 + lg * 4 + r;
            float mx = -1e30f;
            #pragma unroll
            for (int kf = 0; kf < 4; ++kf) {
                int key = ks + kf * 16 + l15;
                bool valid = (key <= qrow) && (qrow - key < 512);
                if (valid) mx = fmaxf(mx, sf[kf][r]);
            }
            #pragma unroll
            for (int d2 = 1; d2 < 16; d2 <<= 1) mx = fmaxf(mx, __shfl_xor(mx, d2));
            tmax[r] = mx;
        }

        float alpha[4], rsum[4];
        #pragma unroll
        for (int r = 0; r < 4; ++r) {
            float mnew = fmaxf(m_run[r], tmax[r]);
            alpha[r] = exp2f((m_run[r] - mnew) * SC);
            m_run[r] = mnew;
            rsum[r] = 0.f;
        }

        unsigned short* Pw = Pl + w * (16 * 72);
        #pragma unroll
        for (int kf = 0; kf < 4; ++kf) {
            #pragma unroll
            for (int r = 0; r < 4; ++r) {
                int qrow = q0 + w * 16 + lg * 4 + r;
                int key = ks + kf * 16 + l15;
                bool valid = (key <= qrow) && (qrow - key < 512);
                float p = valid ? exp2f((sf[kf][r] - m_run[r]) * SC) : 0.f;
                rsum[r] += p;
                Pw[(lg * 4 + r) * 72 + kf * 16 + l15] = f2b(p);
            }
        }
        #pragma unroll
        for (int r = 0; r < 4; ++r) {
            #pragma unroll
            for (int d2 = 1; d2 < 16; d2 <<= 1) rsum[r] += __shfl_xor(rsum[r], d2);
            l_run[r] = l_run[r] * alpha[r] + rsum[r];
        }
        #pragma unroll
        for (int hf = 0; hf < 4; ++hf)
            #pragma unroll
            for (int r = 0; r < 4; ++r) o[hf][r] *= alpha[r];

        asm volatile("s_waitcnt lgkmcnt(0)" ::: "memory");
        __builtin_amdgcn_sched_barrier(0);

        #pragma unroll
        for (int kk2 = 0; kk2 < 2; ++kk2) {
            s16x8 pa = *(const s16x8*)(Pw + l15 * 72 + kk2 * 32 + lg * 8);
            #pragma unroll
            for (int hf = 0; hf < 4; ++hf) {
                s16x8 vb = *(const s16x8*)(Vt + (hf * 16 + l15) * 72 + kk2 * 32 + lg * 8);
                o[hf] = mfma16(pa, vb, o[hf]);
            }
        }
    }

    #pragma unroll
    for (int r = 0; r < 4; ++r) {
        int qrow = q0 + w * 16 + lg * 4 + r;
        float invl = 1.0f / l_run[r];
        unsigned short* orow = out + (size_t)qrow * 2048 + h * 64;
        #pragma unroll
        for (int hf = 0; hf < 4; ++hf)
            orow[hf * 16 + l15] = f2b(o[hf][r] * invl);
    }
}

extern "C" void kernel_launch(void* const* d_in, const int* in_sizes, int n_in,
                              void* d_out, int out_size, void* d_ws, size_t ws_size,
                              hipStream_t stream)
{
    const float* hidden = (const float*)d_in[0];
    const float* w_mix  = (const float*)d_in[1];
    const float* wq     = (const float*)d_in[2];
    const float* wk     = (const float*)d_in[3];
    const float* wv     = (const float*)d_in[4];
    const float* wo     = (const float*)d_in[5];
    const float* w_mlp  = (const float*)d_in[6];
    const float* wg     = (const float*)d_in[7];
    const float* wd     = (const float*)d_in[8];
    float* out = (float*)d_out;

    char* ws = (char*)d_ws;
    size_t off = 0;
    auto alloc = [&](size_t bytes) {
        char* p = ws + off;
        off += (bytes + 255) & ~(size_t)255;
        return p;
    };
    unsigned short* Wt   = (unsigned short*)alloc((size_t)11264 * 2048 * 2);
    unsigned short* xn   = (unsigned short*)alloc((size_t)4096 * 2048 * 2);
    unsigned short* qkv  = (unsigned short*)alloc((size_t)4096 * 3072 * 2);
    float2*         rtab = (float2*)alloc((size_t)4096 * 32 * 8);
    unsigned short* attn = (unsigned short*)alloc((size_t)4096 * 2048 * 2);
    float*          hbuf = (float*)alloc((size_t)4096 * 2048 * 4);
    unsigned short* act  = (unsigned short*)alloc((size_t)4096 * 5632 * 2);

    // 1. x = rmsnorm(hidden) -> bf16
    rmsnorm_bf16<<<4096, 256, 0, stream>>>(hidden, w_mix, xn);

    // 2. W^T for q,k,v concatenated  (grid = (N/64, K/64))
    transpose_to_bf16<<<dim3(32, 32), 256, 0, stream>>>(wq, Wt, 2048, 2048);
    transpose_to_bf16<<<dim3(8, 32), 256, 0, stream>>>(wk, Wt + (size_t)2048 * 2048, 2048, 512);
    transpose_to_bf16<<<dim3(8, 32), 256, 0, stream>>>(wv, Wt + (size_t)2560 * 2048, 2048, 512);

    // 3. qkv = x @ [wq|wk|wv]   (N=3072) 256x256 tiles -> 192 blocks
    gemmq<256, 0><<<192, 512, 0, stream>>>(xn, Wt, qkv, nullptr, 3072, 2048);

    // 4. RoPE
    rope_tab_k<<<(4096 * 32 + 255) / 256, 256, 0, stream>>>(rtab);
    rope_apply_k<<<(4096 * 40 * 4 + 255) / 256, 256, 0, stream>>>(qkv, rtab);

    // 5. sliding-window attention
    attn_swa<<<dim3(64, 32), 256, 0, stream>>>(qkv, attn);

    // 6. h = hidden + attn @ wo   (N=2048) 256x128 tiles -> 256 blocks
    transpose_to_bf16<<<dim3(32, 32), 256, 0, stream>>>(wo, Wt, 2048, 2048);
    gemmq<128, 1><<<256, 512, 0, stream>>>(attn, Wt, hbuf, hidden, 2048, 2048);

    // 7. xn2 = rmsnorm(h)
    rmsnorm_bf16<<<4096, 256, 0, stream>>>(hbuf, w_mlp, xn);

    // 8. MLP: act = silu(x@wg_gate^T) * (x@wg_y^T)  -- one dual-B kernel, 704 blocks
    transpose_to_bf16<<<dim3(176, 32), 256, 0, stream>>>(wg, Wt, 2048, 11264);
    gemm_glu<<<704, 512, 0, stream>>>(xn, Wt, Wt + (size_t)5632 * 2048, act, 5632, 2048);

    // 9. out = h + act @ w_down   (N=2048, K=5632) 256x128 tiles -> 256 blocks
    transpose_to_bf16<<<dim3(32, 88), 256, 0, stream>>>(wd, Wt, 5632, 2048);
    gemmq<128, 1><<<256, 512, 0, stream>>>(act, Wt, out, hbuf, 2048, 5632);
}